// Round 6
// baseline (475.530 us; speedup 1.0000x reference)
//
#include <hip/hip_runtime.h>
#include <hip/hip_bf16.h>
#include <math.h>

#define NPTS   4096
#define NB     4
#define NC     61
#define NK     16
#define NROWS  16384           // NB*NPTS
#define BN_EPS 1e-5f
#define INV_ROWS (1.0f/16384.0f)

#define GRD    8
#define NCELL  512             // 8^3
#define CELLH  0.125f

// ---------------------------------------------------------------------------
// Kernel 0: pack pos -> float4, compute cell id, histogram cells.
// ---------------------------------------------------------------------------
__global__ __launch_bounds__(256) void prep_kernel(const float* __restrict__ pos,
                                                   float4* __restrict__ pos4,
                                                   int* __restrict__ cellOf,
                                                   int* __restrict__ counts) {
    const int i = blockIdx.x * 256 + threadIdx.x;
    if (i >= NB * NPTS) return;
    const float px = pos[i * 3 + 0], py = pos[i * 3 + 1], pz = pos[i * 3 + 2];
    pos4[i] = make_float4(px, py, pz, 0.f);
    const int cx = min(GRD - 1, max(0, (int)(px * GRD)));   // *8 exact in fp32
    const int cy = min(GRD - 1, max(0, (int)(py * GRD)));
    const int cz = min(GRD - 1, max(0, (int)(pz * GRD)));
    const int cid = ((cz << 3) + cy) * GRD + cx;
    cellOf[i] = cid;
    atomicAdd(&counts[(i >> 12) * NCELL + cid], 1);
}

// ---------------------------------------------------------------------------
// Kernel 0b: exclusive prefix sum per batch (512 cells). One block per batch.
// ---------------------------------------------------------------------------
__global__ __launch_bounds__(512) void scan_kernel(const int* __restrict__ counts,
                                                   int* __restrict__ cellStart) {
    __shared__ int s[NCELL];
    const int b = blockIdx.x, t = threadIdx.x;
    s[t] = counts[b * NCELL + t];
    __syncthreads();
    for (int off = 1; off < NCELL; off <<= 1) {
        const int v = (t >= off) ? s[t - off] : 0;
        __syncthreads();
        s[t] += v;
        __syncthreads();
    }
    cellStart[b * (NCELL + 1) + t + 1] = s[t];   // inclusive -> shifted = exclusive
    if (t == 0) cellStart[b * (NCELL + 1)] = 0;
}

// ---------------------------------------------------------------------------
// Kernel 0c: scatter points into cell-sorted order; w = batch-local index.
// ---------------------------------------------------------------------------
__global__ __launch_bounds__(256) void scatter_kernel(const float4* __restrict__ pos4,
                                                      const int* __restrict__ cellOf,
                                                      const int* __restrict__ cellStart,
                                                      int* __restrict__ fill,
                                                      float4* __restrict__ spt) {
    const int i = blockIdx.x * 256 + threadIdx.x;
    if (i >= NB * NPTS) return;
    const int b = i >> 12;
    const int cid = cellOf[i];
    const int dst = cellStart[b * (NCELL + 1) + cid] + atomicAdd(&fill[b * NCELL + cid], 1);
    float4 p = pos4[i];
    p.w = __int_as_float(i & 4095);
    spt[(b << 12) + dst] = p;
}

// ---------------------------------------------------------------------------
// Kernel 1: grid KNN (exact top-16 by (d2, idx), uniform data fast path).
// 512 blocks x 256 threads; 32 queries/block, 8 lanes/query. Scans the 3x3x3
// cell block (9 contiguous x-runs). Ring+compact selection (u64 keys), shared
// threshold across the 8 lanes, final 3-round cross-lane bitonic merge.
// Exactness: flag query if d2_16 >= (margin-eps)^2, where margin = distance
// to outer boundary of the block on sides where more cells exist; flagged
// queries are redone brute-force by knn_fallback. (x*8 exact in fp32 => any
// point closer than margin is inside the scanned block.)
// ---------------------------------------------------------------------------
#define OCAP 8
#define NPAD 257

__global__ __launch_bounds__(256) void knn_kernel(const float4* __restrict__ pos4,
                                                  const float4* __restrict__ spt,
                                                  const int* __restrict__ cellStart,
                                                  int* __restrict__ idx_out,
                                                  int* __restrict__ flagcnt,
                                                  int* __restrict__ flaglist) {
    __shared__ unsigned long long buf[OCAP * NPAD];   // 16.4 KB
    const int t  = threadIdx.x;
    const int l8 = t & 7;
    const int q  = blockIdx.x * 32 + (t >> 3);        // global query row
    const int b  = q >> 12;
    const float4* __restrict__ sb = spt + (b << 12);
    const int* __restrict__ cs = cellStart + b * (NCELL + 1);

    const float4 qp = pos4[q];
    const float qx = qp.x, qy = qp.y, qz = qp.z;
    const int cx = min(GRD - 1, max(0, (int)(qx * GRD)));
    const int cy = min(GRD - 1, max(0, (int)(qy * GRD)));
    const int cz = min(GRD - 1, max(0, (int)(qz * GRD)));
    const int x0 = max(0, cx - 1), x1 = min(GRD - 1, cx + 1);

    unsigned long long bk[16];
#pragma unroll
    for (int i = 0; i < 16; ++i) bk[i] = ~0ull;
    unsigned int thr_bits = 0xFFFFFFFFu;
    int owptr = 0;

    auto compact = [&]() {
        unsigned long long od[OCAP];
#pragma unroll
        for (int s = 0; s < OCAP; ++s) {
            const unsigned long long v = buf[s * NPAD + t];
            od[s] = (s < owptr) ? v : ~0ull;
        }
        owptr = 0;
#pragma unroll
        for (int k = 2; k <= 8; k <<= 1) {
#pragma unroll
            for (int j = k >> 1; j > 0; j >>= 1) {
#pragma unroll
                for (int i = 0; i < 8; ++i) {
                    const int l = i ^ j;
                    if (l > i) {
                        const bool up = ((i & k) == 0);
                        const unsigned long long a = od[i], c = od[l];
                        const bool sw = up ? (c < a) : (a < c);
                        od[i] = sw ? c : a;
                        od[l] = sw ? a : c;
                    }
                }
            }
        }
#pragma unroll
        for (int i = 8; i < 16; ++i) {
            const unsigned long long c = od[15 - i];
            bk[i] = (c < bk[i]) ? c : bk[i];
        }
#pragma unroll
        for (int j = 8; j > 0; j >>= 1) {
#pragma unroll
            for (int i = 0; i < 16; ++i) {
                const int l = i ^ j;
                if (l > i) {
                    const unsigned long long a = bk[i], c = bk[l];
                    const bool sw = (c < a);
                    bk[i] = sw ? c : a;
                    bk[l] = sw ? a : c;
                }
            }
        }
        unsigned int th = (unsigned int)(bk[15] >> 32);
#pragma unroll
        for (int m = 1; m <= 4; m <<= 1) {
            const unsigned int o = __shfl_xor(th, m, 8);
            th = (o < th) ? o : th;
        }
        thr_bits = th;
    };

    // 9 padded (zz,yy) rows; each row is one contiguous x-run of cells.
    for (int rz = 0; rz < 3; ++rz) {
        for (int ry = 0; ry < 3; ++ry) {
            const int zz = cz + rz - 1, yy = cy + ry - 1;
            int rs = 0, re = 0;
            if (zz >= 0 && zz < GRD && yy >= 0 && yy < GRD) {
                const int rowb = ((zz << 3) + yy) << 3;
                rs = cs[rowb + x0];
                re = cs[rowb + x1 + 1];
            }
            int p = rs + l8;
            while (__any(p < re)) {
                if (p < re) {
                    const float4 c = sb[p];
                    const float dx = qx - c.x, dy = qy - c.y, dz = qz - c.z;
                    const float d2 = __fadd_rn(__fadd_rn(__fmul_rn(dx, dx), __fmul_rn(dy, dy)),
                                               __fmul_rn(dz, dz));
                    if (__float_as_uint(d2) < thr_bits) {
                        buf[owptr * NPAD + t] =
                            ((unsigned long long)__float_as_uint(d2) << 32) |
                            (unsigned int)__float_as_int(c.w);
                        owptr++;
                    }
                }
                p += 8;
                if (__any(owptr >= OCAP - 1)) compact();
            }
        }
    }
    compact();   // bk = exact sorted top-16 of this lane's slice of the block

    // 3-round cross-lane bitonic merge over the 8 lanes of the query.
#pragma unroll
    for (int m = 1; m <= 4; m <<= 1) {
        unsigned long long ot[16];
#pragma unroll
        for (int i = 0; i < 16; ++i) ot[i] = __shfl_xor(bk[i], m, 8);
#pragma unroll
        for (int i = 0; i < 16; ++i) {
            const unsigned long long c = ot[15 - i];
            bk[i] = (c < bk[i]) ? c : bk[i];
        }
#pragma unroll
        for (int j = 8; j > 0; j >>= 1) {
#pragma unroll
            for (int i = 0; i < 16; ++i) {
                const int l = i ^ j;
                if (l > i) {
                    const unsigned long long a = bk[i], c = bk[l];
                    const bool sw = (c < a);
                    bk[i] = sw ? c : a;
                    bk[l] = sw ? a : c;
                }
            }
        }
    }

    if (l8 == 0) {
        const int ob = q * NK;
        *(int4*)&idx_out[ob + 0]  = make_int4((int)bk[0],  (int)bk[1],  (int)bk[2],  (int)bk[3]);
        *(int4*)&idx_out[ob + 4]  = make_int4((int)bk[4],  (int)bk[5],  (int)bk[6],  (int)bk[7]);
        *(int4*)&idx_out[ob + 8]  = make_int4((int)bk[8],  (int)bk[9],  (int)bk[10], (int)bk[11]);
        *(int4*)&idx_out[ob + 12] = make_int4((int)bk[12], (int)bk[13], (int)bk[14], (int)bk[15]);

        // exactness margin check
        const int y0 = max(0, cy - 1), y1 = min(GRD - 1, cy + 1);
        const int z0 = max(0, cz - 1), z1 = min(GRD - 1, cz + 1);
        float mg = 1e30f;
        if (x0 > 0)       mg = fminf(mg, qx - x0 * CELLH);
        if (x1 < GRD - 1) mg = fminf(mg, (x1 + 1) * CELLH - qx);
        if (y0 > 0)       mg = fminf(mg, qy - y0 * CELLH);
        if (y1 < GRD - 1) mg = fminf(mg, (y1 + 1) * CELLH - qy);
        if (z0 > 0)       mg = fminf(mg, qz - z0 * CELLH);
        if (z1 < GRD - 1) mg = fminf(mg, (z1 + 1) * CELLH - qz);
        mg = fmaxf(mg - 1e-5f, 0.f);
        const float mg2 = mg * mg;
        if ((unsigned int)(bk[15] >> 32) >= __float_as_uint(mg2)) {
            const int slot = atomicAdd(flagcnt, 1);
            flaglist[slot] = q;
        }
    }
}

// ---------------------------------------------------------------------------
// Kernel 1b: brute-force fallback for flagged queries (exact, full scan).
// 32 blocks x 256; 16 lanes/query; per-lane sorted u64 insert over 256 cands.
// ---------------------------------------------------------------------------
__global__ __launch_bounds__(256) void knn_fallback(const float4* __restrict__ pos4,
                                                    int* __restrict__ idx_out,
                                                    const int* __restrict__ flagcnt,
                                                    const int* __restrict__ flaglist) {
    __shared__ unsigned long long pub[256 * 16];   // 32 KB
    const int t = threadIdx.x;
    const int l16 = t & 15;
    const int grp = (blockIdx.x << 4) + (t >> 4);  // 512 groups total
    const int nf = flagcnt[0];

    for (int fi0 = 0; fi0 < nf; fi0 += 512) {
        const int fi = fi0 + grp;
        const bool qok = (fi < nf);
        const int qi = qok ? flaglist[fi] : 0;
        const int b = qi >> 12;
        const float4* __restrict__ pb = pos4 + (b << 12);
        const float4 qp = pb[qi & 4095];

        unsigned long long bk[16];
#pragma unroll
        for (int i = 0; i < 16; ++i) bk[i] = ~0ull;
        if (qok) {
            for (int s = 0; s < 256; ++s) {
                const int j = (s << 4) | l16;
                const float4 c = pb[j];
                const float dx = qp.x - c.x, dy = qp.y - c.y, dz = qp.z - c.z;
                const float d2 = __fadd_rn(__fadd_rn(__fmul_rn(dx, dx), __fmul_rn(dy, dy)),
                                           __fmul_rn(dz, dz));
                const unsigned long long key =
                    ((unsigned long long)__float_as_uint(d2) << 32) | (unsigned int)j;
                if (key < bk[15]) {
                    bk[15] = key;
#pragma unroll
                    for (int i = 15; i > 0; --i) {
                        const unsigned long long a = bk[i - 1], cc = bk[i];
                        const bool sw = cc < a;
                        bk[i - 1] = sw ? cc : a;
                        bk[i]     = sw ? a : cc;
                    }
                }
            }
        }
#pragma unroll
        for (int s = 0; s < 16; ++s) pub[t * 16 + s] = bk[s];
        __syncthreads();
        if (qok && l16 == 0) {
            unsigned long long heads[16];
            int hp[16];
            const int base = t;          // group's first thread slab index
#pragma unroll
            for (int L = 0; L < 16; ++L) { hp[L] = 0; heads[L] = pub[(base + L) * 16]; }
            const int ob = qi * NK;
            for (int o = 0; o < NK; ++o) {
                unsigned long long bestk = heads[0];
                int bestL = 0;
#pragma unroll
                for (int L = 1; L < 16; ++L) {
                    const bool bt = heads[L] < bestk;
                    bestk = bt ? heads[L] : bestk;
                    bestL = bt ? L : bestL;
                }
                idx_out[ob + o] = (int)(bestk & 0xFFFFFFFFu);
#pragma unroll
                for (int L = 0; L < 16; ++L) {
                    if (L == bestL) {
                        hp[L]++;
                        heads[L] = (hp[L] < 16) ? pub[(base + L) * 16 + hp[L]] : ~0ull;
                    }
                }
            }
        }
        __syncthreads();
    }
}

// ---------------------------------------------------------------------------
// Kernel 2: relation MLP (10->32->64->64) + weighted max-pool over K.
// (unchanged from round 5: 2 items/thread, bf16-packed layer-2/3 weights)
// ---------------------------------------------------------------------------
__device__ __forceinline__ unsigned int f2bf(float f) {   // RNE to bf16 bits
    unsigned int b = __float_as_uint(f);
    return (b + 0x7FFFu + ((b >> 16) & 1u)) >> 16;
}
#define BFLO(u) __uint_as_float((u) << 16)
#define BFHI(u) __uint_as_float((u) & 0xFFFF0000u)

__global__ __launch_bounds__(256) void mlp_kernel(
    const float4* __restrict__ pos4, const float* __restrict__ x,
    const int* __restrict__ idx,
    const float* __restrict__ rw1, const float* __restrict__ rb1,
    const float* __restrict__ rw2, const float* __restrict__ rb2,
    const float* __restrict__ rw3, const float* __restrict__ rb3,
    float* __restrict__ pooled) {
    __shared__ float w1s[320], b1s[32], b2s[64], b3s[64];
    __shared__ unsigned int w2p[1024];
    __shared__ unsigned int w3p[2048];
    const int t = threadIdx.x;
    for (int i = t; i < 320; i += 256)  w1s[i] = rw1[i];
    for (int i = t; i < 1024; i += 256) {
        const int row = i >> 5, q = i & 31;
        w2p[i] = f2bf(rw2[row * 64 + 2 * q]) | (f2bf(rw2[row * 64 + 2 * q + 1]) << 16);
    }
    for (int i = t; i < 2048; i += 256) {
        const int o = i >> 5, q = i & 31;
        w3p[i] = f2bf(rw3[(2 * q) * 64 + o]) | (f2bf(rw3[(2 * q + 1) * 64 + o]) << 16);
    }
    if (t < 32)                 b1s[t] = rb1[t];
    else if (t >= 32 && t < 96) b2s[t - 32] = rb2[t - 32];
    else if (t >= 96 && t < 160) b3s[t - 96] = rb3[t - 96];
    __syncthreads();

    const int k8   = t & 7;
    const int qloc = t >> 3;
    const int q    = blockIdx.x * 32 + qloc;
    const int b    = q >> 12, n = q & 4095;
    const int j0 = idx[(size_t)q * NK + k8];
    const int j1 = idx[(size_t)q * NK + k8 + 8];
    const float4* __restrict__ pb = pos4 + (b << 12);

    const float4 cp = pb[n];
    const float4 pa = pb[j0];
    const float4 pc = pb[j1];
    const float rxa = pa.x - cp.x, rya = pa.y - cp.y, rza = pa.z - cp.z;
    const float rxb = pc.x - cp.x, ryb = pc.y - cp.y, rzb = pc.z - cp.z;
    const float ssa = rxa * rxa + rya * rya + rza * rza;
    const float ssb = rxb * rxb + ryb * ryb + rzb * rzb;
    const float disa = (ssa > 0.f) ? sqrtf(ssa) : 0.f;
    const float disb = (ssb > 0.f) ? sqrtf(ssb) : 0.f;
    const float rina[10] = {cp.x, cp.y, cp.z, pa.x, pa.y, pa.z, rxa, rya, rza, disa};
    const float rinb[10] = {cp.x, cp.y, cp.z, pc.x, pc.y, pc.z, rxb, ryb, rzb, disb};

    float h1a[32], h1b[32];
#pragma unroll
    for (int o = 0; o < 32; ++o) { h1a[o] = b1s[o]; h1b[o] = h1a[o]; }
#pragma unroll
    for (int i = 0; i < 10; ++i) {
        const float va = rina[i], vb = rinb[i];
#pragma unroll
        for (int o = 0; o < 32; ++o) {
            const float w = w1s[i * 32 + o];
            h1a[o] += va * w; h1b[o] += vb * w;
        }
    }
#pragma unroll
    for (int o = 0; o < 32; ++o) { h1a[o] = fmaxf(h1a[o], 0.f); h1b[o] = fmaxf(h1b[o], 0.f); }

    float h2a[64], h2b[64];
#pragma unroll
    for (int o = 0; o < 64; ++o) { h2a[o] = b2s[o]; h2b[o] = h2a[o]; }
    for (int i = 0; i < 32; ++i) {
        const float va = h1a[i], vb = h1b[i];
#pragma unroll
        for (int op = 0; op < 8; ++op) {
            const uint4 u = *(const uint4*)&w2p[(i << 5) + (op << 2)];
            const int o = op << 3;
            const float w0 = BFLO(u.x), w1 = BFHI(u.x), w2 = BFLO(u.y), w3 = BFHI(u.y);
            const float w4 = BFLO(u.z), w5 = BFHI(u.z), w6 = BFLO(u.w), w7 = BFHI(u.w);
            h2a[o+0] += va*w0; h2b[o+0] += vb*w0;
            h2a[o+1] += va*w1; h2b[o+1] += vb*w1;
            h2a[o+2] += va*w2; h2b[o+2] += vb*w2;
            h2a[o+3] += va*w3; h2b[o+3] += vb*w3;
            h2a[o+4] += va*w4; h2b[o+4] += vb*w4;
            h2a[o+5] += va*w5; h2b[o+5] += vb*w5;
            h2a[o+6] += va*w6; h2b[o+6] += vb*w6;
            h2a[o+7] += va*w7; h2b[o+7] += vb*w7;
        }
    }
#pragma unroll
    for (int o = 0; o < 64; ++o) { h2a[o] = fmaxf(h2a[o], 0.f); h2b[o] = fmaxf(h2b[o], 0.f); }

    const float* __restrict__ xr0 = x + (size_t)((b << 12) | j0) * NC;
    const float* __restrict__ xr1 = x + (size_t)((b << 12) | j1) * NC;
    float* __restrict__ pout = pooled + (size_t)q * 64;

    for (int o = 0; o < 64; ++o) {
        float acca = b3s[o], accb = acca;
#pragma unroll
        for (int ip = 0; ip < 8; ++ip) {
            const uint4 u = *(const uint4*)&w3p[(o << 5) + (ip << 2)];
            const int i = ip << 3;
            const float w0 = BFLO(u.x), w1 = BFHI(u.x), w2 = BFLO(u.y), w3 = BFHI(u.y);
            const float w4 = BFLO(u.z), w5 = BFHI(u.z), w6 = BFLO(u.w), w7 = BFHI(u.w);
            acca += h2a[i+0]*w0 + h2a[i+1]*w1 + h2a[i+2]*w2 + h2a[i+3]*w3
                  + h2a[i+4]*w4 + h2a[i+5]*w5 + h2a[i+6]*w6 + h2a[i+7]*w7;
            accb += h2b[i+0]*w0 + h2b[i+1]*w1 + h2b[i+2]*w2 + h2b[i+3]*w3
                  + h2b[i+4]*w4 + h2b[i+5]*w5 + h2b[i+6]*w6 + h2b[i+7]*w7;
        }
        const float fa = (o < NC) ? xr0[o] : (o == 61 ? pa.x : (o == 62 ? pa.y : pa.z));
        const float fb = (o < NC) ? xr1[o] : (o == 61 ? pc.x : (o == 62 ? pc.y : pc.z));
        float f = fmaxf(fa * acca, fb * accb);
#pragma unroll
        for (int m = 1; m < 8; m <<= 1) f = fmaxf(f, __shfl_xor(f, m, 8));
        if (k8 == 0) pout[o] = fmaxf(f, 0.f);
    }
}

// ---------------------------------------------------------------------------
// Kernel 3: y1 = pooled(16384x64) @ fw1(64x128) + fb1 ; accumulate sum/sumsq.
// ---------------------------------------------------------------------------
__global__ __launch_bounds__(256) void gemm1_kernel(
    const float* __restrict__ A, const float* __restrict__ W,
    const float* __restrict__ bias, float* __restrict__ y,
    float* __restrict__ sum, float* __restrict__ sumsq) {
    __shared__ float As[64 * 64];
    __shared__ float Bs[64 * 128];
    const int t = threadIdx.x;
    const int r0 = blockIdx.x * 64;
    for (int i = t; i < 64 * 128; i += 256) Bs[i] = W[i];
    for (int i = t; i < 64 * 64; i += 256)  As[i] = A[(size_t)r0 * 64 + i];
    __syncthreads();

    const int c = t & 127, rg = t >> 7;
    float acc[32];
    const float bv = bias[c];
#pragma unroll
    for (int r = 0; r < 32; ++r) acc[r] = bv;

    for (int kk = 0; kk < 64; kk += 4) {
        const float b0 = Bs[(kk + 0) * 128 + c];
        const float b1 = Bs[(kk + 1) * 128 + c];
        const float b2 = Bs[(kk + 2) * 128 + c];
        const float b3 = Bs[(kk + 3) * 128 + c];
#pragma unroll
        for (int r = 0; r < 32; ++r) {
            const float4 a = *(const float4*)&As[(rg * 32 + r) * 64 + kk];
            acc[r] += a.x * b0 + a.y * b1 + a.z * b2 + a.w * b3;
        }
    }

    float s = 0.f, s2 = 0.f;
#pragma unroll
    for (int r = 0; r < 32; ++r) {
        const float v = acc[r];
        s += v; s2 += v * v;
        y[(size_t)(r0 + rg * 32 + r) * 128 + c] = v;
    }
    __syncthreads();
    As[t] = s; As[256 + t] = s2;
    __syncthreads();
    if (rg == 0) {
        atomicAdd(&sum[c],   As[c] + As[128 + c]);
        atomicAdd(&sumsq[c], As[256 + c] + As[256 + 128 + c]);
    }
}

// ---------------------------------------------------------------------------
// Kernel 4: h1 = relu(bn1(y1)); y2 = h1 @ fw2(128x128) + fb2 ; sum/sumsq.
// ---------------------------------------------------------------------------
__global__ __launch_bounds__(256) void gemm2_kernel(
    const float* __restrict__ y1, const float* __restrict__ W,
    const float* __restrict__ bias,
    const float* __restrict__ sum1, const float* __restrict__ sumsq1,
    const float* __restrict__ g1, const float* __restrict__ b1,
    float* __restrict__ y2, float* __restrict__ sum2, float* __restrict__ sumsq2) {
    __shared__ float As[64 * 128];
    __shared__ float Bs[64 * 128];
    __shared__ float a1s[128], s1s[128];
    const int t = threadIdx.x;
    const int r0 = blockIdx.x * 64;

    if (t < 128) {
        const float m = sum1[t] * INV_ROWS;
        const float v = sumsq1[t] * INV_ROWS - m * m;
        const float a = rsqrtf(v + BN_EPS) * g1[t];
        a1s[t] = a; s1s[t] = b1[t] - m * a;
    }
    for (int i = t; i < 64 * 128; i += 256) Bs[i] = W[i];
    __syncthreads();
    for (int i = t; i < 64 * 128; i += 256) {
        const int cc = i & 127;
        const float v = y1[(size_t)r0 * 128 + i];
        As[i] = fmaxf(v * a1s[cc] + s1s[cc], 0.f);
    }
    __syncthreads();

    const int c = t & 127, rg = t >> 7;
    float acc[32];
    const float bv = bias[c];
#pragma unroll
    for (int r = 0; r < 32; ++r) acc[r] = bv;

    for (int kk = 0; kk < 64; kk += 4) {
        const float b0 = Bs[(kk + 0) * 128 + c];
        const float b1v = Bs[(kk + 1) * 128 + c];
        const float b2 = Bs[(kk + 2) * 128 + c];
        const float b3 = Bs[(kk + 3) * 128 + c];
#pragma unroll
        for (int r = 0; r < 32; ++r) {
            const float4 a = *(const float4*)&As[(rg * 32 + r) * 128 + kk];
            acc[r] += a.x * b0 + a.y * b1v + a.z * b2 + a.w * b3;
        }
    }
    __syncthreads();
    for (int i = t; i < 64 * 128; i += 256) Bs[i] = W[64 * 128 + i];
    __syncthreads();
    for (int kk = 0; kk < 64; kk += 4) {
        const float b0 = Bs[(kk + 0) * 128 + c];
        const float b1v = Bs[(kk + 1) * 128 + c];
        const float b2 = Bs[(kk + 2) * 128 + c];
        const float b3 = Bs[(kk + 3) * 128 + c];
#pragma unroll
        for (int r = 0; r < 32; ++r) {
            const float4 a = *(const float4*)&As[(rg * 32 + r) * 128 + 64 + kk];
            acc[r] += a.x * b0 + a.y * b1v + a.z * b2 + a.w * b3;
        }
    }

    float s = 0.f, s2 = 0.f;
#pragma unroll
    for (int r = 0; r < 32; ++r) {
        const float v = acc[r];
        s += v; s2 += v * v;
        y2[(size_t)(r0 + rg * 32 + r) * 128 + c] = v;
    }
    __syncthreads();
    As[t] = s; As[256 + t] = s2;
    __syncthreads();
    if (rg == 0) {
        atomicAdd(&sum2[c],   As[c] + As[128 + c]);
        atomicAdd(&sumsq2[c], As[256 + c] + As[256 + 128 + c]);
    }
}

// ---------------------------------------------------------------------------
// Kernel 5: out = bn2(y2)
// ---------------------------------------------------------------------------
__global__ __launch_bounds__(256) void bnout_kernel(
    const float* __restrict__ y2, const float* __restrict__ sum2,
    const float* __restrict__ sumsq2, const float* __restrict__ g2,
    const float* __restrict__ b2, float* __restrict__ out) {
    const int i = blockIdx.x * 256 + threadIdx.x;
    const int c = i & 127;
    const float m = sum2[c] * INV_ROWS;
    const float v = sumsq2[c] * INV_ROWS - m * m;
    const float a = rsqrtf(v + BN_EPS) * g2[c];
    out[i] = y2[i] * a + (b2[c] - m * a);
}

extern "C" void kernel_launch(void* const* d_in, const int* in_sizes, int n_in,
                              void* d_out, int out_size, void* d_ws, size_t ws_size,
                              hipStream_t stream) {
    const float* x   = (const float*)d_in[0];
    const float* pos = (const float*)d_in[1];
    const float* rw1 = (const float*)d_in[2];
    const float* rb1 = (const float*)d_in[3];
    const float* rw2 = (const float*)d_in[4];
    const float* rb2 = (const float*)d_in[5];
    const float* rw3 = (const float*)d_in[6];
    const float* rb3 = (const float*)d_in[7];
    const float* fw1 = (const float*)d_in[8];
    const float* fb1 = (const float*)d_in[9];
    const float* g1  = (const float*)d_in[10];
    const float* b1  = (const float*)d_in[11];
    const float* fw2 = (const float*)d_in[12];
    const float* fb2 = (const float*)d_in[13];
    const float* g2  = (const float*)d_in[14];
    const float* b2  = (const float*)d_in[15];
    float* out = (float*)d_out;

    char* ws = (char*)d_ws;
    int*    idx      = (int*)ws;                           // 1 MB
    float*  pooled   = (float*)(ws + (1u << 20));          // 4 MB
    float*  y1       = (float*)(ws + (5u << 20));          // 8 MB
    float*  y2       = (float*)(ws + (13u << 20));         // 8 MB
    float*  stats    = (float*)(ws + (21u << 20));         // zeroed block start
    float*  sum1 = stats, *sumsq1 = stats + 128, *sum2 = stats + 256, *sumsq2 = stats + 384;
    int*    counts   = (int*)(stats + 512);                // 4*512
    int*    fill     = counts + NB * NCELL;                // 4*512
    int*    flagcnt  = fill + NB * NCELL;                  // 1
    int*    cellStart= (int*)(ws + (21u << 20) + (20u << 10));  // 4*513 ints
    int*    cellOf   = (int*)(ws + (21u << 20) + (32u << 10));  // 16384 ints
    int*    flaglist = (int*)(ws + (21u << 20) + (96u << 10));  // 16384 ints
    float4* pos4     = (float4*)(ws + (22u << 20));        // 256 KB
    float4* spt      = (float4*)(ws + (22u << 20) + (256u << 10)); // 256 KB

    // zero: stats(512f) + counts(2048i) + fill(2048i) + flagcnt(1i)
    hipMemsetAsync(stats, 0, (512 + 2048 + 2048 + 1) * sizeof(float), stream);

    prep_kernel<<<64, 256, 0, stream>>>(pos, pos4, cellOf, counts);
    scan_kernel<<<NB, 512, 0, stream>>>(counts, cellStart);
    scatter_kernel<<<64, 256, 0, stream>>>(pos4, cellOf, cellStart, fill, spt);
    knn_kernel<<<512, 256, 0, stream>>>(pos4, spt, cellStart, idx, flagcnt, flaglist);
    knn_fallback<<<32, 256, 0, stream>>>(pos4, idx, flagcnt, flaglist);
    mlp_kernel<<<512, 256, 0, stream>>>(pos4, x, idx, rw1, rb1, rw2, rb2, rw3, rb3, pooled);
    gemm1_kernel<<<256, 256, 0, stream>>>(pooled, fw1, fb1, y1, sum1, sumsq1);
    gemm2_kernel<<<256, 256, 0, stream>>>(y1, fw2, fb2, sum1, sumsq1, g1, b1, y2, sum2, sumsq2);
    bnout_kernel<<<NROWS * 128 / 256, 256, 0, stream>>>(y2, sum2, sumsq2, g2, b2, out);
}

// Round 7
// 320.699 us; speedup vs baseline: 1.4828x; 1.4828x over previous
//
#include <hip/hip_runtime.h>
#include <hip/hip_bf16.h>
#include <math.h>

#define NPTS   4096
#define NB     4
#define NC     61
#define NK     16
#define NROWS  16384           // NB*NPTS
#define BN_EPS 1e-5f
#define INV_ROWS (1.0f/16384.0f)

#define GRD    8
#define NCELL  512             // 8^3
#define CELLH  0.125f

// ---------------------------------------------------------------------------
// Kernel 0: pack pos -> float4, compute cell id, histogram cells.
// ---------------------------------------------------------------------------
__global__ __launch_bounds__(256) void prep_kernel(const float* __restrict__ pos,
                                                   float4* __restrict__ pos4,
                                                   int* __restrict__ cellOf,
                                                   int* __restrict__ counts) {
    const int i = blockIdx.x * 256 + threadIdx.x;
    if (i >= NB * NPTS) return;
    const float px = pos[i * 3 + 0], py = pos[i * 3 + 1], pz = pos[i * 3 + 2];
    pos4[i] = make_float4(px, py, pz, 0.f);
    const int cx = min(GRD - 1, max(0, (int)(px * GRD)));   // *8 exact in fp32
    const int cy = min(GRD - 1, max(0, (int)(py * GRD)));
    const int cz = min(GRD - 1, max(0, (int)(pz * GRD)));
    const int cid = ((cz << 3) + cy) * GRD + cx;
    cellOf[i] = cid;
    atomicAdd(&counts[(i >> 12) * NCELL + cid], 1);
}

// ---------------------------------------------------------------------------
// Kernel 0b: exclusive prefix sum per batch (512 cells). One block per batch.
// ---------------------------------------------------------------------------
__global__ __launch_bounds__(512) void scan_kernel(const int* __restrict__ counts,
                                                   int* __restrict__ cellStart) {
    __shared__ int s[NCELL];
    const int b = blockIdx.x, t = threadIdx.x;
    s[t] = counts[b * NCELL + t];
    __syncthreads();
    for (int off = 1; off < NCELL; off <<= 1) {
        const int v = (t >= off) ? s[t - off] : 0;
        __syncthreads();
        s[t] += v;
        __syncthreads();
    }
    cellStart[b * (NCELL + 1) + t + 1] = s[t];   // inclusive -> shifted = exclusive
    if (t == 0) cellStart[b * (NCELL + 1)] = 0;
}

// ---------------------------------------------------------------------------
// Kernel 0c: scatter points into cell-sorted order; w = batch-local index.
// ---------------------------------------------------------------------------
__global__ __launch_bounds__(256) void scatter_kernel(const float4* __restrict__ pos4,
                                                      const int* __restrict__ cellOf,
                                                      const int* __restrict__ cellStart,
                                                      int* __restrict__ fill,
                                                      float4* __restrict__ spt) {
    const int i = blockIdx.x * 256 + threadIdx.x;
    if (i >= NB * NPTS) return;
    const int b = i >> 12;
    const int cid = cellOf[i];
    const int dst = cellStart[b * (NCELL + 1) + cid] + atomicAdd(&fill[b * NCELL + cid], 1);
    float4 p = pos4[i];
    p.w = __int_as_float(i & 4095);
    spt[(b << 12) + dst] = p;
}

// ---------------------------------------------------------------------------
// Kernel 1: grid KNN (exact top-16 by (d2, idx), uniform data fast path).
// 512 blocks x 256 threads; 32 queries/block, 8 lanes/query. Scans the 3x3x3
// cell block (9 contiguous x-runs). Ring+compact selection (u64 keys), shared
// threshold across the 8 lanes, final 3-round cross-lane bitonic merge.
// Flagged queries (margin test) are redone brute-force by knn_fallback.
// ---------------------------------------------------------------------------
#define OCAP 8
#define NPAD 257

__global__ __launch_bounds__(256) void knn_kernel(const float4* __restrict__ pos4,
                                                  const float4* __restrict__ spt,
                                                  const int* __restrict__ cellStart,
                                                  int* __restrict__ idx_out,
                                                  int* __restrict__ flagcnt,
                                                  int* __restrict__ flaglist) {
    __shared__ unsigned long long buf[OCAP * NPAD];   // 16.4 KB
    const int t  = threadIdx.x;
    const int l8 = t & 7;
    const int q  = blockIdx.x * 32 + (t >> 3);        // global query row
    const int b  = q >> 12;
    const float4* __restrict__ sb = spt + (b << 12);
    const int* __restrict__ cs = cellStart + b * (NCELL + 1);

    const float4 qp = pos4[q];
    const float qx = qp.x, qy = qp.y, qz = qp.z;
    const int cx = min(GRD - 1, max(0, (int)(qx * GRD)));
    const int cy = min(GRD - 1, max(0, (int)(qy * GRD)));
    const int cz = min(GRD - 1, max(0, (int)(qz * GRD)));
    const int x0 = max(0, cx - 1), x1 = min(GRD - 1, cx + 1);

    unsigned long long bk[16];
#pragma unroll
    for (int i = 0; i < 16; ++i) bk[i] = ~0ull;
    unsigned int thr_bits = 0xFFFFFFFFu;
    int owptr = 0;

    auto compact = [&]() {
        unsigned long long od[OCAP];
#pragma unroll
        for (int s = 0; s < OCAP; ++s) {
            const unsigned long long v = buf[s * NPAD + t];
            od[s] = (s < owptr) ? v : ~0ull;
        }
        owptr = 0;
#pragma unroll
        for (int k = 2; k <= 8; k <<= 1) {
#pragma unroll
            for (int j = k >> 1; j > 0; j >>= 1) {
#pragma unroll
                for (int i = 0; i < 8; ++i) {
                    const int l = i ^ j;
                    if (l > i) {
                        const bool up = ((i & k) == 0);
                        const unsigned long long a = od[i], c = od[l];
                        const bool sw = up ? (c < a) : (a < c);
                        od[i] = sw ? c : a;
                        od[l] = sw ? a : c;
                    }
                }
            }
        }
#pragma unroll
        for (int i = 8; i < 16; ++i) {
            const unsigned long long c = od[15 - i];
            bk[i] = (c < bk[i]) ? c : bk[i];
        }
#pragma unroll
        for (int j = 8; j > 0; j >>= 1) {
#pragma unroll
            for (int i = 0; i < 16; ++i) {
                const int l = i ^ j;
                if (l > i) {
                    const unsigned long long a = bk[i], c = bk[l];
                    const bool sw = (c < a);
                    bk[i] = sw ? c : a;
                    bk[l] = sw ? a : c;
                }
            }
        }
        unsigned int th = (unsigned int)(bk[15] >> 32);
#pragma unroll
        for (int m = 1; m <= 4; m <<= 1) {
            const unsigned int o = __shfl_xor(th, m, 8);
            th = (o < th) ? o : th;
        }
        thr_bits = th;
    };

    // 9 padded (zz,yy) rows; each row is one contiguous x-run of cells.
    for (int rz = 0; rz < 3; ++rz) {
        for (int ry = 0; ry < 3; ++ry) {
            const int zz = cz + rz - 1, yy = cy + ry - 1;
            int rs = 0, re = 0;
            if (zz >= 0 && zz < GRD && yy >= 0 && yy < GRD) {
                const int rowb = ((zz << 3) + yy) << 3;
                rs = cs[rowb + x0];
                re = cs[rowb + x1 + 1];
            }
            int p = rs + l8;
            while (__any(p < re)) {
                if (p < re) {
                    const float4 c = sb[p];
                    const float dx = qx - c.x, dy = qy - c.y, dz = qz - c.z;
                    const float d2 = __fadd_rn(__fadd_rn(__fmul_rn(dx, dx), __fmul_rn(dy, dy)),
                                               __fmul_rn(dz, dz));
                    if (__float_as_uint(d2) < thr_bits) {
                        buf[owptr * NPAD + t] =
                            ((unsigned long long)__float_as_uint(d2) << 32) |
                            (unsigned int)__float_as_int(c.w);
                        owptr++;
                    }
                }
                p += 8;
                if (__any(owptr >= OCAP - 1)) compact();
            }
        }
    }
    compact();   // bk = exact sorted top-16 of this lane's slice of the block

    // 3-round cross-lane bitonic merge over the 8 lanes of the query.
#pragma unroll
    for (int m = 1; m <= 4; m <<= 1) {
        unsigned long long ot[16];
#pragma unroll
        for (int i = 0; i < 16; ++i) ot[i] = __shfl_xor(bk[i], m, 8);
#pragma unroll
        for (int i = 0; i < 16; ++i) {
            const unsigned long long c = ot[15 - i];
            bk[i] = (c < bk[i]) ? c : bk[i];
        }
#pragma unroll
        for (int j = 8; j > 0; j >>= 1) {
#pragma unroll
            for (int i = 0; i < 16; ++i) {
                const int l = i ^ j;
                if (l > i) {
                    const unsigned long long a = bk[i], c = bk[l];
                    const bool sw = (c < a);
                    bk[i] = sw ? c : a;
                    bk[l] = sw ? a : c;
                }
            }
        }
    }

    if (l8 == 0) {
        const int ob = q * NK;
        *(int4*)&idx_out[ob + 0]  = make_int4((int)bk[0],  (int)bk[1],  (int)bk[2],  (int)bk[3]);
        *(int4*)&idx_out[ob + 4]  = make_int4((int)bk[4],  (int)bk[5],  (int)bk[6],  (int)bk[7]);
        *(int4*)&idx_out[ob + 8]  = make_int4((int)bk[8],  (int)bk[9],  (int)bk[10], (int)bk[11]);
        *(int4*)&idx_out[ob + 12] = make_int4((int)bk[12], (int)bk[13], (int)bk[14], (int)bk[15]);

        // exactness margin check
        const int y0 = max(0, cy - 1), y1 = min(GRD - 1, cy + 1);
        const int z0 = max(0, cz - 1), z1 = min(GRD - 1, cz + 1);
        float mg = 1e30f;
        if (x0 > 0)       mg = fminf(mg, qx - x0 * CELLH);
        if (x1 < GRD - 1) mg = fminf(mg, (x1 + 1) * CELLH - qx);
        if (y0 > 0)       mg = fminf(mg, qy - y0 * CELLH);
        if (y1 < GRD - 1) mg = fminf(mg, (y1 + 1) * CELLH - qy);
        if (z0 > 0)       mg = fminf(mg, qz - z0 * CELLH);
        if (z1 < GRD - 1) mg = fminf(mg, (z1 + 1) * CELLH - qz);
        mg = fmaxf(mg - 1e-5f, 0.f);
        const float mg2 = mg * mg;
        if ((unsigned int)(bk[15] >> 32) >= __float_as_uint(mg2)) {
            const int slot = atomicAdd(flagcnt, 1);
            flaglist[slot] = q;
        }
    }
}

// ---------------------------------------------------------------------------
// Kernel 1b: brute-force fallback, ONE BLOCK PER FLAGGED QUERY (grid-stride).
// 256 threads x 16 coalesced float4 candidates -> register bitonic sort-16 ->
// 6-round cross-lane (width-64) bitonic merge -> 4 per-wave lists in LDS ->
// single-thread 4-way merge. Same u64 keys => identical ordering semantics.
// Round-6 version had ~6 active groups serially scanning 4096 points at
// single-wave latency (200 us, VALUBusy 0.6%); this spreads each query
// across a full block and all flagged queries across CUs.
// ---------------------------------------------------------------------------
__global__ __launch_bounds__(256) void knn_fallback(const float4* __restrict__ pos4,
                                                    int* __restrict__ idx_out,
                                                    const int* __restrict__ flagcnt,
                                                    const int* __restrict__ flaglist) {
    __shared__ unsigned long long wres[4 * 16];
    const int nf = flagcnt[0];
    const int t = threadIdx.x;
    const int w = t >> 6;

    for (int fi = blockIdx.x; fi < nf; fi += 64) {
        const int qi = flaglist[fi];
        const int b = qi >> 12;
        const float4* __restrict__ pb = pos4 + (b << 12);
        const float4 qp = pb[qi & 4095];

        // 16 coalesced candidates per thread: j = s*256 + t
        float4 c[16];
#pragma unroll
        for (int s = 0; s < 16; ++s) c[s] = pb[(s << 8) | t];

        unsigned long long key[16];
#pragma unroll
        for (int s = 0; s < 16; ++s) {
            const int j = (s << 8) | t;
            const float dx = qp.x - c[s].x, dy = qp.y - c[s].y, dz = qp.z - c[s].z;
            const float d2 = __fadd_rn(__fadd_rn(__fmul_rn(dx, dx), __fmul_rn(dy, dy)),
                                       __fmul_rn(dz, dz));
            key[s] = ((unsigned long long)__float_as_uint(d2) << 32) | (unsigned int)j;
        }

        // full bitonic sort of key[16] ascending
#pragma unroll
        for (int k = 2; k <= 16; k <<= 1) {
#pragma unroll
            for (int j = k >> 1; j > 0; j >>= 1) {
#pragma unroll
                for (int i = 0; i < 16; ++i) {
                    const int l = i ^ j;
                    if (l > i) {
                        const bool up = ((i & k) == 0);
                        const unsigned long long a = key[i], cc = key[l];
                        const bool sw = up ? (cc < a) : (a < cc);
                        key[i] = sw ? cc : a;
                        key[l] = sw ? a : cc;
                    }
                }
            }
        }

        // 6-round cross-lane bitonic merge across the 64-lane wave
#pragma unroll
        for (int m = 1; m <= 32; m <<= 1) {
            unsigned long long ot[16];
#pragma unroll
            for (int i = 0; i < 16; ++i) ot[i] = __shfl_xor(key[i], m, 64);
#pragma unroll
            for (int i = 0; i < 16; ++i) {
                const unsigned long long cc = ot[15 - i];
                key[i] = (cc < key[i]) ? cc : key[i];
            }
#pragma unroll
            for (int j = 8; j > 0; j >>= 1) {
#pragma unroll
                for (int i = 0; i < 16; ++i) {
                    const int l = i ^ j;
                    if (l > i) {
                        const unsigned long long a = key[i], cc = key[l];
                        const bool sw = (cc < a);
                        key[i] = sw ? cc : a;
                        key[l] = sw ? a : cc;
                    }
                }
            }
        }

        if ((t & 63) == 0) {
#pragma unroll
            for (int i = 0; i < 16; ++i) wres[w * 16 + i] = key[i];
        }
        __syncthreads();

        if (t == 0) {
            int hp[4] = {0, 0, 0, 0};
            const int ob = qi * NK;
            for (int o = 0; o < NK; ++o) {
                unsigned long long bestk = ~0ull;
                int bestw = 0;
#pragma unroll
                for (int w2 = 0; w2 < 4; ++w2) {
                    const unsigned long long h = (hp[w2] < 16) ? wres[w2 * 16 + hp[w2]] : ~0ull;
                    if (h < bestk) { bestk = h; bestw = w2; }
                }
                idx_out[ob + o] = (int)(bestk & 0xFFFFFFFFu);
                hp[bestw]++;
            }
        }
        __syncthreads();
    }
}

// ---------------------------------------------------------------------------
// Kernel 2: relation MLP (10->32->64->64) + weighted max-pool over K.
// (unchanged: 2 items/thread, bf16-packed layer-2/3 weights)
// ---------------------------------------------------------------------------
__device__ __forceinline__ unsigned int f2bf(float f) {   // RNE to bf16 bits
    unsigned int b = __float_as_uint(f);
    return (b + 0x7FFFu + ((b >> 16) & 1u)) >> 16;
}
#define BFLO(u) __uint_as_float((u) << 16)
#define BFHI(u) __uint_as_float((u) & 0xFFFF0000u)

__global__ __launch_bounds__(256) void mlp_kernel(
    const float4* __restrict__ pos4, const float* __restrict__ x,
    const int* __restrict__ idx,
    const float* __restrict__ rw1, const float* __restrict__ rb1,
    const float* __restrict__ rw2, const float* __restrict__ rb2,
    const float* __restrict__ rw3, const float* __restrict__ rb3,
    float* __restrict__ pooled) {
    __shared__ float w1s[320], b1s[32], b2s[64], b3s[64];
    __shared__ unsigned int w2p[1024];
    __shared__ unsigned int w3p[2048];
    const int t = threadIdx.x;
    for (int i = t; i < 320; i += 256)  w1s[i] = rw1[i];
    for (int i = t; i < 1024; i += 256) {
        const int row = i >> 5, q = i & 31;
        w2p[i] = f2bf(rw2[row * 64 + 2 * q]) | (f2bf(rw2[row * 64 + 2 * q + 1]) << 16);
    }
    for (int i = t; i < 2048; i += 256) {
        const int o = i >> 5, q = i & 31;
        w3p[i] = f2bf(rw3[(2 * q) * 64 + o]) | (f2bf(rw3[(2 * q + 1) * 64 + o]) << 16);
    }
    if (t < 32)                 b1s[t] = rb1[t];
    else if (t >= 32 && t < 96) b2s[t - 32] = rb2[t - 32];
    else if (t >= 96 && t < 160) b3s[t - 96] = rb3[t - 96];
    __syncthreads();

    const int k8   = t & 7;
    const int qloc = t >> 3;
    const int q    = blockIdx.x * 32 + qloc;
    const int b    = q >> 12, n = q & 4095;
    const int j0 = idx[(size_t)q * NK + k8];
    const int j1 = idx[(size_t)q * NK + k8 + 8];
    const float4* __restrict__ pb = pos4 + (b << 12);

    const float4 cp = pb[n];
    const float4 pa = pb[j0];
    const float4 pc = pb[j1];
    const float rxa = pa.x - cp.x, rya = pa.y - cp.y, rza = pa.z - cp.z;
    const float rxb = pc.x - cp.x, ryb = pc.y - cp.y, rzb = pc.z - cp.z;
    const float ssa = rxa * rxa + rya * rya + rza * rza;
    const float ssb = rxb * rxb + ryb * ryb + rzb * rzb;
    const float disa = (ssa > 0.f) ? sqrtf(ssa) : 0.f;
    const float disb = (ssb > 0.f) ? sqrtf(ssb) : 0.f;
    const float rina[10] = {cp.x, cp.y, cp.z, pa.x, pa.y, pa.z, rxa, rya, rza, disa};
    const float rinb[10] = {cp.x, cp.y, cp.z, pc.x, pc.y, pc.z, rxb, ryb, rzb, disb};

    float h1a[32], h1b[32];
#pragma unroll
    for (int o = 0; o < 32; ++o) { h1a[o] = b1s[o]; h1b[o] = h1a[o]; }
#pragma unroll
    for (int i = 0; i < 10; ++i) {
        const float va = rina[i], vb = rinb[i];
#pragma unroll
        for (int o = 0; o < 32; ++o) {
            const float w = w1s[i * 32 + o];
            h1a[o] += va * w; h1b[o] += vb * w;
        }
    }
#pragma unroll
    for (int o = 0; o < 32; ++o) { h1a[o] = fmaxf(h1a[o], 0.f); h1b[o] = fmaxf(h1b[o], 0.f); }

    float h2a[64], h2b[64];
#pragma unroll
    for (int o = 0; o < 64; ++o) { h2a[o] = b2s[o]; h2b[o] = h2a[o]; }
    for (int i = 0; i < 32; ++i) {
        const float va = h1a[i], vb = h1b[i];
#pragma unroll
        for (int op = 0; op < 8; ++op) {
            const uint4 u = *(const uint4*)&w2p[(i << 5) + (op << 2)];
            const int o = op << 3;
            const float w0 = BFLO(u.x), w1 = BFHI(u.x), w2 = BFLO(u.y), w3 = BFHI(u.y);
            const float w4 = BFLO(u.z), w5 = BFHI(u.z), w6 = BFLO(u.w), w7 = BFHI(u.w);
            h2a[o+0] += va*w0; h2b[o+0] += vb*w0;
            h2a[o+1] += va*w1; h2b[o+1] += vb*w1;
            h2a[o+2] += va*w2; h2b[o+2] += vb*w2;
            h2a[o+3] += va*w3; h2b[o+3] += vb*w3;
            h2a[o+4] += va*w4; h2b[o+4] += vb*w4;
            h2a[o+5] += va*w5; h2b[o+5] += vb*w5;
            h2a[o+6] += va*w6; h2b[o+6] += vb*w6;
            h2a[o+7] += va*w7; h2b[o+7] += vb*w7;
        }
    }
#pragma unroll
    for (int o = 0; o < 64; ++o) { h2a[o] = fmaxf(h2a[o], 0.f); h2b[o] = fmaxf(h2b[o], 0.f); }

    const float* __restrict__ xr0 = x + (size_t)((b << 12) | j0) * NC;
    const float* __restrict__ xr1 = x + (size_t)((b << 12) | j1) * NC;
    float* __restrict__ pout = pooled + (size_t)q * 64;

    for (int o = 0; o < 64; ++o) {
        float acca = b3s[o], accb = acca;
#pragma unroll
        for (int ip = 0; ip < 8; ++ip) {
            const uint4 u = *(const uint4*)&w3p[(o << 5) + (ip << 2)];
            const int i = ip << 3;
            const float w0 = BFLO(u.x), w1 = BFHI(u.x), w2 = BFLO(u.y), w3 = BFHI(u.y);
            const float w4 = BFLO(u.z), w5 = BFHI(u.z), w6 = BFLO(u.w), w7 = BFHI(u.w);
            acca += h2a[i+0]*w0 + h2a[i+1]*w1 + h2a[i+2]*w2 + h2a[i+3]*w3
                  + h2a[i+4]*w4 + h2a[i+5]*w5 + h2a[i+6]*w6 + h2a[i+7]*w7;
            accb += h2b[i+0]*w0 + h2b[i+1]*w1 + h2b[i+2]*w2 + h2b[i+3]*w3
                  + h2b[i+4]*w4 + h2b[i+5]*w5 + h2b[i+6]*w6 + h2b[i+7]*w7;
        }
        const float fa = (o < NC) ? xr0[o] : (o == 61 ? pa.x : (o == 62 ? pa.y : pa.z));
        const float fb = (o < NC) ? xr1[o] : (o == 61 ? pc.x : (o == 62 ? pc.y : pc.z));
        float f = fmaxf(fa * acca, fb * accb);
#pragma unroll
        for (int m = 1; m < 8; m <<= 1) f = fmaxf(f, __shfl_xor(f, m, 8));
        if (k8 == 0) pout[o] = fmaxf(f, 0.f);
    }
}

// ---------------------------------------------------------------------------
// Kernel 3: y1 = pooled(16384x64) @ fw1(64x128) + fb1 ; accumulate sum/sumsq.
// ---------------------------------------------------------------------------
__global__ __launch_bounds__(256) void gemm1_kernel(
    const float* __restrict__ A, const float* __restrict__ W,
    const float* __restrict__ bias, float* __restrict__ y,
    float* __restrict__ sum, float* __restrict__ sumsq) {
    __shared__ float As[64 * 64];
    __shared__ float Bs[64 * 128];
    const int t = threadIdx.x;
    const int r0 = blockIdx.x * 64;
    for (int i = t; i < 64 * 128; i += 256) Bs[i] = W[i];
    for (int i = t; i < 64 * 64; i += 256)  As[i] = A[(size_t)r0 * 64 + i];
    __syncthreads();

    const int c = t & 127, rg = t >> 7;
    float acc[32];
    const float bv = bias[c];
#pragma unroll
    for (int r = 0; r < 32; ++r) acc[r] = bv;

    for (int kk = 0; kk < 64; kk += 4) {
        const float b0 = Bs[(kk + 0) * 128 + c];
        const float b1 = Bs[(kk + 1) * 128 + c];
        const float b2 = Bs[(kk + 2) * 128 + c];
        const float b3 = Bs[(kk + 3) * 128 + c];
#pragma unroll
        for (int r = 0; r < 32; ++r) {
            const float4 a = *(const float4*)&As[(rg * 32 + r) * 64 + kk];
            acc[r] += a.x * b0 + a.y * b1 + a.z * b2 + a.w * b3;
        }
    }

    float s = 0.f, s2 = 0.f;
#pragma unroll
    for (int r = 0; r < 32; ++r) {
        const float v = acc[r];
        s += v; s2 += v * v;
        y[(size_t)(r0 + rg * 32 + r) * 128 + c] = v;
    }
    __syncthreads();
    As[t] = s; As[256 + t] = s2;
    __syncthreads();
    if (rg == 0) {
        atomicAdd(&sum[c],   As[c] + As[128 + c]);
        atomicAdd(&sumsq[c], As[256 + c] + As[256 + 128 + c]);
    }
}

// ---------------------------------------------------------------------------
// Kernel 4: h1 = relu(bn1(y1)); y2 = h1 @ fw2(128x128) + fb2 ; sum/sumsq.
// ---------------------------------------------------------------------------
__global__ __launch_bounds__(256) void gemm2_kernel(
    const float* __restrict__ y1, const float* __restrict__ W,
    const float* __restrict__ bias,
    const float* __restrict__ sum1, const float* __restrict__ sumsq1,
    const float* __restrict__ g1, const float* __restrict__ b1,
    float* __restrict__ y2, float* __restrict__ sum2, float* __restrict__ sumsq2) {
    __shared__ float As[64 * 128];
    __shared__ float Bs[64 * 128];
    __shared__ float a1s[128], s1s[128];
    const int t = threadIdx.x;
    const int r0 = blockIdx.x * 64;

    if (t < 128) {
        const float m = sum1[t] * INV_ROWS;
        const float v = sumsq1[t] * INV_ROWS - m * m;
        const float a = rsqrtf(v + BN_EPS) * g1[t];
        a1s[t] = a; s1s[t] = b1[t] - m * a;
    }
    for (int i = t; i < 64 * 128; i += 256) Bs[i] = W[i];
    __syncthreads();
    for (int i = t; i < 64 * 128; i += 256) {
        const int cc = i & 127;
        const float v = y1[(size_t)r0 * 128 + i];
        As[i] = fmaxf(v * a1s[cc] + s1s[cc], 0.f);
    }
    __syncthreads();

    const int c = t & 127, rg = t >> 7;
    float acc[32];
    const float bv = bias[c];
#pragma unroll
    for (int r = 0; r < 32; ++r) acc[r] = bv;

    for (int kk = 0; kk < 64; kk += 4) {
        const float b0 = Bs[(kk + 0) * 128 + c];
        const float b1v = Bs[(kk + 1) * 128 + c];
        const float b2 = Bs[(kk + 2) * 128 + c];
        const float b3 = Bs[(kk + 3) * 128 + c];
#pragma unroll
        for (int r = 0; r < 32; ++r) {
            const float4 a = *(const float4*)&As[(rg * 32 + r) * 128 + kk];
            acc[r] += a.x * b0 + a.y * b1v + a.z * b2 + a.w * b3;
        }
    }
    __syncthreads();
    for (int i = t; i < 64 * 128; i += 256) Bs[i] = W[64 * 128 + i];
    __syncthreads();
    for (int kk = 0; kk < 64; kk += 4) {
        const float b0 = Bs[(kk + 0) * 128 + c];
        const float b1v = Bs[(kk + 1) * 128 + c];
        const float b2 = Bs[(kk + 2) * 128 + c];
        const float b3 = Bs[(kk + 3) * 128 + c];
#pragma unroll
        for (int r = 0; r < 32; ++r) {
            const float4 a = *(const float4*)&As[(rg * 32 + r) * 128 + 64 + kk];
            acc[r] += a.x * b0 + a.y * b1v + a.z * b2 + a.w * b3;
        }
    }

    float s = 0.f, s2 = 0.f;
#pragma unroll
    for (int r = 0; r < 32; ++r) {
        const float v = acc[r];
        s += v; s2 += v * v;
        y2[(size_t)(r0 + rg * 32 + r) * 128 + c] = v;
    }
    __syncthreads();
    As[t] = s; As[256 + t] = s2;
    __syncthreads();
    if (rg == 0) {
        atomicAdd(&sum2[c],   As[c] + As[128 + c]);
        atomicAdd(&sumsq2[c], As[256 + c] + As[256 + 128 + c]);
    }
}

// ---------------------------------------------------------------------------
// Kernel 5: out = bn2(y2)
// ---------------------------------------------------------------------------
__global__ __launch_bounds__(256) void bnout_kernel(
    const float* __restrict__ y2, const float* __restrict__ sum2,
    const float* __restrict__ sumsq2, const float* __restrict__ g2,
    const float* __restrict__ b2, float* __restrict__ out) {
    const int i = blockIdx.x * 256 + threadIdx.x;
    const int c = i & 127;
    const float m = sum2[c] * INV_ROWS;
    const float v = sumsq2[c] * INV_ROWS - m * m;
    const float a = rsqrtf(v + BN_EPS) * g2[c];
    out[i] = y2[i] * a + (b2[c] - m * a);
}

extern "C" void kernel_launch(void* const* d_in, const int* in_sizes, int n_in,
                              void* d_out, int out_size, void* d_ws, size_t ws_size,
                              hipStream_t stream) {
    const float* x   = (const float*)d_in[0];
    const float* pos = (const float*)d_in[1];
    const float* rw1 = (const float*)d_in[2];
    const float* rb1 = (const float*)d_in[3];
    const float* rw2 = (const float*)d_in[4];
    const float* rb2 = (const float*)d_in[5];
    const float* rw3 = (const float*)d_in[6];
    const float* rb3 = (const float*)d_in[7];
    const float* fw1 = (const float*)d_in[8];
    const float* fb1 = (const float*)d_in[9];
    const float* g1  = (const float*)d_in[10];
    const float* b1  = (const float*)d_in[11];
    const float* fw2 = (const float*)d_in[12];
    const float* fb2 = (const float*)d_in[13];
    const float* g2  = (const float*)d_in[14];
    const float* b2  = (const float*)d_in[15];
    float* out = (float*)d_out;

    char* ws = (char*)d_ws;
    int*    idx      = (int*)ws;                           // 1 MB
    float*  pooled   = (float*)(ws + (1u << 20));          // 4 MB
    float*  y1       = (float*)(ws + (5u << 20));          // 8 MB
    float*  y2       = (float*)(ws + (13u << 20));         // 8 MB
    float*  stats    = (float*)(ws + (21u << 20));         // zeroed block start
    float*  sum1 = stats, *sumsq1 = stats + 128, *sum2 = stats + 256, *sumsq2 = stats + 384;
    int*    counts   = (int*)(stats + 512);                // 4*512
    int*    fill     = counts + NB * NCELL;                // 4*512
    int*    flagcnt  = fill + NB * NCELL;                  // 1
    int*    cellStart= (int*)(ws + (21u << 20) + (20u << 10));  // 4*513 ints
    int*    cellOf   = (int*)(ws + (21u << 20) + (32u << 10));  // 16384 ints
    int*    flaglist = (int*)(ws + (21u << 20) + (96u << 10));  // 16384 ints
    float4* pos4     = (float4*)(ws + (22u << 20));        // 256 KB
    float4* spt      = (float4*)(ws + (22u << 20) + (256u << 10)); // 256 KB

    // zero: stats(512f) + counts(2048i) + fill(2048i) + flagcnt(1i)
    hipMemsetAsync(stats, 0, (512 + 2048 + 2048 + 1) * sizeof(float), stream);

    prep_kernel<<<64, 256, 0, stream>>>(pos, pos4, cellOf, counts);
    scan_kernel<<<NB, 512, 0, stream>>>(counts, cellStart);
    scatter_kernel<<<64, 256, 0, stream>>>(pos4, cellOf, cellStart, fill, spt);
    knn_kernel<<<512, 256, 0, stream>>>(pos4, spt, cellStart, idx, flagcnt, flaglist);
    knn_fallback<<<64, 256, 0, stream>>>(pos4, idx, flagcnt, flaglist);
    mlp_kernel<<<512, 256, 0, stream>>>(pos4, x, idx, rw1, rb1, rw2, rb2, rw3, rb3, pooled);
    gemm1_kernel<<<256, 256, 0, stream>>>(pooled, fw1, fb1, y1, sum1, sumsq1);
    gemm2_kernel<<<256, 256, 0, stream>>>(y1, fw2, fb2, sum1, sumsq1, g1, b1, y2, sum2, sumsq2);
    bnout_kernel<<<NROWS * 128 / 256, 256, 0, stream>>>(y2, sum2, sumsq2, g2, b2, out);
}

// Round 8
// 260.668 us; speedup vs baseline: 1.8243x; 1.2303x over previous
//
#include <hip/hip_runtime.h>
#include <hip/hip_bf16.h>
#include <math.h>

#define NPTS   4096
#define NB     4
#define NC     61
#define NK     16
#define NROWS  16384           // NB*NPTS
#define BN_EPS 1e-5f
#define INV_ROWS (1.0f/16384.0f)

#define GRD    8
#define NCELL  512             // 8^3
#define CELLH  0.125f

typedef short bf16x8 __attribute__((ext_vector_type(8)));
typedef float f32x4  __attribute__((ext_vector_type(4)));

// ---------------------------------------------------------------------------
// Kernel 0: pack pos -> float4, compute cell id, histogram cells.
// ---------------------------------------------------------------------------
__global__ __launch_bounds__(256) void prep_kernel(const float* __restrict__ pos,
                                                   float4* __restrict__ pos4,
                                                   int* __restrict__ cellOf,
                                                   int* __restrict__ counts) {
    const int i = blockIdx.x * 256 + threadIdx.x;
    if (i >= NB * NPTS) return;
    const float px = pos[i * 3 + 0], py = pos[i * 3 + 1], pz = pos[i * 3 + 2];
    pos4[i] = make_float4(px, py, pz, 0.f);
    const int cx = min(GRD - 1, max(0, (int)(px * GRD)));   // *8 exact in fp32
    const int cy = min(GRD - 1, max(0, (int)(py * GRD)));
    const int cz = min(GRD - 1, max(0, (int)(pz * GRD)));
    const int cid = ((cz << 3) + cy) * GRD + cx;
    cellOf[i] = cid;
    atomicAdd(&counts[(i >> 12) * NCELL + cid], 1);
}

// ---------------------------------------------------------------------------
// Kernel 0b: exclusive prefix sum per batch (512 cells). One block per batch.
// ---------------------------------------------------------------------------
__global__ __launch_bounds__(512) void scan_kernel(const int* __restrict__ counts,
                                                   int* __restrict__ cellStart) {
    __shared__ int s[NCELL];
    const int b = blockIdx.x, t = threadIdx.x;
    s[t] = counts[b * NCELL + t];
    __syncthreads();
    for (int off = 1; off < NCELL; off <<= 1) {
        const int v = (t >= off) ? s[t - off] : 0;
        __syncthreads();
        s[t] += v;
        __syncthreads();
    }
    cellStart[b * (NCELL + 1) + t + 1] = s[t];   // inclusive -> shifted = exclusive
    if (t == 0) cellStart[b * (NCELL + 1)] = 0;
}

// ---------------------------------------------------------------------------
// Kernel 0c: scatter points into cell-sorted order; w = batch-local index.
// ---------------------------------------------------------------------------
__global__ __launch_bounds__(256) void scatter_kernel(const float4* __restrict__ pos4,
                                                      const int* __restrict__ cellOf,
                                                      const int* __restrict__ cellStart,
                                                      int* __restrict__ fill,
                                                      float4* __restrict__ spt) {
    const int i = blockIdx.x * 256 + threadIdx.x;
    if (i >= NB * NPTS) return;
    const int b = i >> 12;
    const int cid = cellOf[i];
    const int dst = cellStart[b * (NCELL + 1) + cid] + atomicAdd(&fill[b * NCELL + cid], 1);
    float4 p = pos4[i];
    p.w = __int_as_float(i & 4095);
    spt[(b << 12) + dst] = p;
}

// ---------------------------------------------------------------------------
// Kernel 1: grid KNN (unchanged from round 7).
// ---------------------------------------------------------------------------
#define OCAP 8
#define NPAD 257

__global__ __launch_bounds__(256) void knn_kernel(const float4* __restrict__ pos4,
                                                  const float4* __restrict__ spt,
                                                  const int* __restrict__ cellStart,
                                                  int* __restrict__ idx_out,
                                                  int* __restrict__ flagcnt,
                                                  int* __restrict__ flaglist) {
    __shared__ unsigned long long buf[OCAP * NPAD];   // 16.4 KB
    const int t  = threadIdx.x;
    const int l8 = t & 7;
    const int q  = blockIdx.x * 32 + (t >> 3);        // global query row
    const int b  = q >> 12;
    const float4* __restrict__ sb = spt + (b << 12);
    const int* __restrict__ cs = cellStart + b * (NCELL + 1);

    const float4 qp = pos4[q];
    const float qx = qp.x, qy = qp.y, qz = qp.z;
    const int cx = min(GRD - 1, max(0, (int)(qx * GRD)));
    const int cy = min(GRD - 1, max(0, (int)(qy * GRD)));
    const int cz = min(GRD - 1, max(0, (int)(qz * GRD)));
    const int x0 = max(0, cx - 1), x1 = min(GRD - 1, cx + 1);

    unsigned long long bk[16];
#pragma unroll
    for (int i = 0; i < 16; ++i) bk[i] = ~0ull;
    unsigned int thr_bits = 0xFFFFFFFFu;
    int owptr = 0;

    auto compact = [&]() {
        unsigned long long od[OCAP];
#pragma unroll
        for (int s = 0; s < OCAP; ++s) {
            const unsigned long long v = buf[s * NPAD + t];
            od[s] = (s < owptr) ? v : ~0ull;
        }
        owptr = 0;
#pragma unroll
        for (int k = 2; k <= 8; k <<= 1) {
#pragma unroll
            for (int j = k >> 1; j > 0; j >>= 1) {
#pragma unroll
                for (int i = 0; i < 8; ++i) {
                    const int l = i ^ j;
                    if (l > i) {
                        const bool up = ((i & k) == 0);
                        const unsigned long long a = od[i], c = od[l];
                        const bool sw = up ? (c < a) : (a < c);
                        od[i] = sw ? c : a;
                        od[l] = sw ? a : c;
                    }
                }
            }
        }
#pragma unroll
        for (int i = 8; i < 16; ++i) {
            const unsigned long long c = od[15 - i];
            bk[i] = (c < bk[i]) ? c : bk[i];
        }
#pragma unroll
        for (int j = 8; j > 0; j >>= 1) {
#pragma unroll
            for (int i = 0; i < 16; ++i) {
                const int l = i ^ j;
                if (l > i) {
                    const unsigned long long a = bk[i], c = bk[l];
                    const bool sw = (c < a);
                    bk[i] = sw ? c : a;
                    bk[l] = sw ? a : c;
                }
            }
        }
        unsigned int th = (unsigned int)(bk[15] >> 32);
#pragma unroll
        for (int m = 1; m <= 4; m <<= 1) {
            const unsigned int o = __shfl_xor(th, m, 8);
            th = (o < th) ? o : th;
        }
        thr_bits = th;
    };

    for (int rz = 0; rz < 3; ++rz) {
        for (int ry = 0; ry < 3; ++ry) {
            const int zz = cz + rz - 1, yy = cy + ry - 1;
            int rs = 0, re = 0;
            if (zz >= 0 && zz < GRD && yy >= 0 && yy < GRD) {
                const int rowb = ((zz << 3) + yy) << 3;
                rs = cs[rowb + x0];
                re = cs[rowb + x1 + 1];
            }
            int p = rs + l8;
            while (__any(p < re)) {
                if (p < re) {
                    const float4 c = sb[p];
                    const float dx = qx - c.x, dy = qy - c.y, dz = qz - c.z;
                    const float d2 = __fadd_rn(__fadd_rn(__fmul_rn(dx, dx), __fmul_rn(dy, dy)),
                                               __fmul_rn(dz, dz));
                    if (__float_as_uint(d2) < thr_bits) {
                        buf[owptr * NPAD + t] =
                            ((unsigned long long)__float_as_uint(d2) << 32) |
                            (unsigned int)__float_as_int(c.w);
                        owptr++;
                    }
                }
                p += 8;
                if (__any(owptr >= OCAP - 1)) compact();
            }
        }
    }
    compact();

#pragma unroll
    for (int m = 1; m <= 4; m <<= 1) {
        unsigned long long ot[16];
#pragma unroll
        for (int i = 0; i < 16; ++i) ot[i] = __shfl_xor(bk[i], m, 8);
#pragma unroll
        for (int i = 0; i < 16; ++i) {
            const unsigned long long c = ot[15 - i];
            bk[i] = (c < bk[i]) ? c : bk[i];
        }
#pragma unroll
        for (int j = 8; j > 0; j >>= 1) {
#pragma unroll
            for (int i = 0; i < 16; ++i) {
                const int l = i ^ j;
                if (l > i) {
                    const unsigned long long a = bk[i], c = bk[l];
                    const bool sw = (c < a);
                    bk[i] = sw ? c : a;
                    bk[l] = sw ? a : c;
                }
            }
        }
    }

    if (l8 == 0) {
        const int ob = q * NK;
        *(int4*)&idx_out[ob + 0]  = make_int4((int)bk[0],  (int)bk[1],  (int)bk[2],  (int)bk[3]);
        *(int4*)&idx_out[ob + 4]  = make_int4((int)bk[4],  (int)bk[5],  (int)bk[6],  (int)bk[7]);
        *(int4*)&idx_out[ob + 8]  = make_int4((int)bk[8],  (int)bk[9],  (int)bk[10], (int)bk[11]);
        *(int4*)&idx_out[ob + 12] = make_int4((int)bk[12], (int)bk[13], (int)bk[14], (int)bk[15]);

        const int y0 = max(0, cy - 1), y1 = min(GRD - 1, cy + 1);
        const int z0 = max(0, cz - 1), z1 = min(GRD - 1, cz + 1);
        float mg = 1e30f;
        if (x0 > 0)       mg = fminf(mg, qx - x0 * CELLH);
        if (x1 < GRD - 1) mg = fminf(mg, (x1 + 1) * CELLH - qx);
        if (y0 > 0)       mg = fminf(mg, qy - y0 * CELLH);
        if (y1 < GRD - 1) mg = fminf(mg, (y1 + 1) * CELLH - qy);
        if (z0 > 0)       mg = fminf(mg, qz - z0 * CELLH);
        if (z1 < GRD - 1) mg = fminf(mg, (z1 + 1) * CELLH - qz);
        mg = fmaxf(mg - 1e-5f, 0.f);
        const float mg2 = mg * mg;
        if ((unsigned int)(bk[15] >> 32) >= __float_as_uint(mg2)) {
            const int slot = atomicAdd(flagcnt, 1);
            flaglist[slot] = q;
        }
    }
}

// ---------------------------------------------------------------------------
// Kernel 1b: brute-force fallback, one block per flagged query (round 7).
// ---------------------------------------------------------------------------
__global__ __launch_bounds__(256) void knn_fallback(const float4* __restrict__ pos4,
                                                    int* __restrict__ idx_out,
                                                    const int* __restrict__ flagcnt,
                                                    const int* __restrict__ flaglist) {
    __shared__ unsigned long long wres[4 * 16];
    const int nf = flagcnt[0];
    const int t = threadIdx.x;
    const int w = t >> 6;

    for (int fi = blockIdx.x; fi < nf; fi += 64) {
        const int qi = flaglist[fi];
        const int b = qi >> 12;
        const float4* __restrict__ pb = pos4 + (b << 12);
        const float4 qp = pb[qi & 4095];

        float4 c[16];
#pragma unroll
        for (int s = 0; s < 16; ++s) c[s] = pb[(s << 8) | t];

        unsigned long long key[16];
#pragma unroll
        for (int s = 0; s < 16; ++s) {
            const int j = (s << 8) | t;
            const float dx = qp.x - c[s].x, dy = qp.y - c[s].y, dz = qp.z - c[s].z;
            const float d2 = __fadd_rn(__fadd_rn(__fmul_rn(dx, dx), __fmul_rn(dy, dy)),
                                       __fmul_rn(dz, dz));
            key[s] = ((unsigned long long)__float_as_uint(d2) << 32) | (unsigned int)j;
        }

#pragma unroll
        for (int k = 2; k <= 16; k <<= 1) {
#pragma unroll
            for (int j = k >> 1; j > 0; j >>= 1) {
#pragma unroll
                for (int i = 0; i < 16; ++i) {
                    const int l = i ^ j;
                    if (l > i) {
                        const bool up = ((i & k) == 0);
                        const unsigned long long a = key[i], cc = key[l];
                        const bool sw = up ? (cc < a) : (a < cc);
                        key[i] = sw ? cc : a;
                        key[l] = sw ? a : cc;
                    }
                }
            }
        }

#pragma unroll
        for (int m = 1; m <= 32; m <<= 1) {
            unsigned long long ot[16];
#pragma unroll
            for (int i = 0; i < 16; ++i) ot[i] = __shfl_xor(key[i], m, 64);
#pragma unroll
            for (int i = 0; i < 16; ++i) {
                const unsigned long long cc = ot[15 - i];
                key[i] = (cc < key[i]) ? cc : key[i];
            }
#pragma unroll
            for (int j = 8; j > 0; j >>= 1) {
#pragma unroll
                for (int i = 0; i < 16; ++i) {
                    const int l = i ^ j;
                    if (l > i) {
                        const unsigned long long a = key[i], cc = key[l];
                        const bool sw = (cc < a);
                        key[i] = sw ? cc : a;
                        key[l] = sw ? a : cc;
                    }
                }
            }
        }

        if ((t & 63) == 0) {
#pragma unroll
            for (int i = 0; i < 16; ++i) wres[w * 16 + i] = key[i];
        }
        __syncthreads();

        if (t == 0) {
            int hp[4] = {0, 0, 0, 0};
            const int ob = qi * NK;
            for (int o = 0; o < NK; ++o) {
                unsigned long long bestk = ~0ull;
                int bestw = 0;
#pragma unroll
                for (int w2 = 0; w2 < 4; ++w2) {
                    const unsigned long long h = (hp[w2] < 16) ? wres[w2 * 16 + hp[w2]] : ~0ull;
                    if (h < bestk) { bestk = h; bestw = w2; }
                }
                idx_out[ob + o] = (int)(bestk & 0xFFFFFFFFu);
                hp[bestw]++;
            }
        }
        __syncthreads();
    }
}

// ---------------------------------------------------------------------------
// Kernel 2: relation MLP via MFMA (16x16x32 bf16).
// 1024 blocks x 256 threads; each wave owns 64 item rows (= 4 queries; rows
// are q*16+k so one 16-row M-tile = one query -> max-pool is in-register).
// Layer1: K=32 padded (rin k0..9, k15=1.0 bias trick, rest 0), 2 N-tiles.
// Layer2: K=32, 4 N-tiles. Layer3: K=64 (2 k-tiles), 4 N-tiles.
// C->A transforms round-trip a per-wave LDS buffer in bf16 (strides 40/72:
// ds_read_b128 pattern <=2-way bank-aliased = free). feat gathered directly
// at C-layout (each instr = 4 rows x 16 consecutive cols, coalesced).
// Layouts (verified, guide §3): A[m=lane&15][k=quad*8+j],
// B[k=quad*8+j][n=lane&15], C[row=quad*4+reg][col=lane&15].
// ---------------------------------------------------------------------------
__device__ __forceinline__ unsigned int f2bf(float f) {   // RNE to bf16 bits
    unsigned int b = __float_as_uint(f);
    return (b + 0x7FFFu + ((b >> 16) & 1u)) >> 16;
}

__global__ __launch_bounds__(256) void mlp_kernel(
    const float4* __restrict__ pos4, const float* __restrict__ x,
    const int* __restrict__ idx,
    const float* __restrict__ rw1, const float* __restrict__ rb1,
    const float* __restrict__ rw2, const float* __restrict__ rb2,
    const float* __restrict__ rw3, const float* __restrict__ rb3,
    float* __restrict__ pooled) {
    __shared__ __attribute__((aligned(16))) unsigned short w1t[32 * 40];  // [n][k]
    __shared__ __attribute__((aligned(16))) unsigned short w2t[64 * 40];  // [n][k]
    __shared__ __attribute__((aligned(16))) unsigned short w3t[64 * 72];  // [n][k]
    __shared__ __attribute__((aligned(16))) unsigned short scr[4 * 64 * 72]; // per-wave

    const int t = threadIdx.x;
    // stage transposed bf16 weights; w1t: k10..14=0, k15=rb1[n], k16..31=0
    for (int i = t; i < 32 * 32; i += 256) {
        const int n = i >> 5, k = i & 31;
        float v = 0.f;
        if (k < 10) v = rw1[k * 32 + n];
        else if (k == 15) v = rb1[n];
        w1t[n * 40 + k] = (unsigned short)f2bf(v);
    }
    for (int i = t; i < 64 * 32; i += 256) {
        const int n = i >> 5, k = i & 31;
        w2t[n * 40 + k] = (unsigned short)f2bf(rw2[k * 64 + n]);
    }
    for (int i = t; i < 64 * 64; i += 256) {
        const int n = i >> 6, k = i & 63;
        w3t[n * 72 + k] = (unsigned short)f2bf(rw3[k * 64 + n]);
    }
    __syncthreads();

    const int lane = t & 63;
    const int quad = lane >> 4;
    const int l16  = lane & 15;
    unsigned short* __restrict__ ws = &scr[(t >> 6) * 64 * 72];

    const int rowbase = blockIdx.x * 256 + (t & 192);   // (t>>6)*64
    const int b = rowbase >> 16;                        // 65536 items per batch
    const float4* __restrict__ pb = pos4 + ((size_t)b << 12);
    const float* __restrict__ xb = x + ((size_t)b << 12) * NC;

    // ---- build rin rows (one per lane), bf16, stride 40; k15 = 1.0 ----
    {
        const int row_g = rowbase + lane;
        const int q = row_g >> 4;
        const int j = idx[row_g];
        const float4 cp = pb[q & 4095];
        const float4 gp = pb[j];
        const float rx = gp.x - cp.x, ry = gp.y - cp.y, rz = gp.z - cp.z;
        const float ss = rx * rx + ry * ry + rz * rz;
        const float dis = (ss > 0.f) ? sqrtf(ss) : 0.f;
        unsigned int d[20];
#pragma unroll
        for (int i = 0; i < 20; ++i) d[i] = 0;
        d[0] = f2bf(cp.x) | (f2bf(cp.y) << 16);
        d[1] = f2bf(cp.z) | (f2bf(gp.x) << 16);
        d[2] = f2bf(gp.y) | (f2bf(gp.z) << 16);
        d[3] = f2bf(rx)   | (f2bf(ry) << 16);
        d[4] = f2bf(rz)   | (f2bf(dis) << 16);
        d[7] = 0x3F800000u;   // k14=0, k15=1.0 (bias slot)
        unsigned int* wr = (unsigned int*)&ws[lane * 40];
#pragma unroll
        for (int i = 0; i < 20; ++i) wr[i] = d[i];
    }
    __builtin_amdgcn_s_waitcnt(0);   // lgkm drain before same-wave read-back

    const f32x4 zero = {0.f, 0.f, 0.f, 0.f};

    // ---- layer 1: 64x32 = A(64x32) @ w1(32x32-padded) ----
    bf16x8 a1[4], b1f[2];
#pragma unroll
    for (int mt = 0; mt < 4; ++mt)
        a1[mt] = *(const bf16x8*)&ws[(mt * 16 + l16) * 40 + quad * 8];
#pragma unroll
    for (int nt = 0; nt < 2; ++nt)
        b1f[nt] = *(const bf16x8*)&w1t[(nt * 16 + l16) * 40 + quad * 8];

    f32x4 c1[2][4];
#pragma unroll
    for (int nt = 0; nt < 2; ++nt)
#pragma unroll
        for (int mt = 0; mt < 4; ++mt)
            c1[nt][mt] = __builtin_amdgcn_mfma_f32_16x16x32_bf16(a1[mt], b1f[nt], zero, 0, 0, 0);

    // relu -> h1 to LDS (stride 40)
#pragma unroll
    for (int nt = 0; nt < 2; ++nt)
#pragma unroll
        for (int mt = 0; mt < 4; ++mt)
#pragma unroll
            for (int r = 0; r < 4; ++r)
                ws[(mt * 16 + quad * 4 + r) * 40 + nt * 16 + l16] =
                    (unsigned short)f2bf(fmaxf(c1[nt][mt][r], 0.f));
    __builtin_amdgcn_s_waitcnt(0);

    // ---- layer 2: 64x64 = h1(64x32) @ w2(32x64) ----
    float b2v[4], b3v[4];
#pragma unroll
    for (int nt = 0; nt < 4; ++nt) { b2v[nt] = rb2[nt * 16 + l16]; b3v[nt] = rb3[nt * 16 + l16]; }

    bf16x8 a2[4];
#pragma unroll
    for (int mt = 0; mt < 4; ++mt)
        a2[mt] = *(const bf16x8*)&ws[(mt * 16 + l16) * 40 + quad * 8];

    f32x4 c2[4][4];
#pragma unroll
    for (int nt = 0; nt < 4; ++nt) {
        const bf16x8 b2f = *(const bf16x8*)&w2t[(nt * 16 + l16) * 40 + quad * 8];
#pragma unroll
        for (int mt = 0; mt < 4; ++mt)
            c2[nt][mt] = __builtin_amdgcn_mfma_f32_16x16x32_bf16(a2[mt], b2f, zero, 0, 0, 0);
    }

    // bias + relu -> h2 to LDS (stride 72)
#pragma unroll
    for (int nt = 0; nt < 4; ++nt)
#pragma unroll
        for (int mt = 0; mt < 4; ++mt)
#pragma unroll
            for (int r = 0; r < 4; ++r)
                ws[(mt * 16 + quad * 4 + r) * 72 + nt * 16 + l16] =
                    (unsigned short)f2bf(fmaxf(c2[nt][mt][r] + b2v[nt], 0.f));
    __builtin_amdgcn_s_waitcnt(0);

    // ---- layer 3: 64x64 = h2(64x64) @ w3(64x64), 2 k-tiles ----
    bf16x8 a3[4][2];
#pragma unroll
    for (int mt = 0; mt < 4; ++mt)
#pragma unroll
        for (int kt = 0; kt < 2; ++kt)
            a3[mt][kt] = *(const bf16x8*)&ws[(mt * 16 + l16) * 72 + kt * 32 + quad * 8];

    f32x4 c3[4][4];
#pragma unroll
    for (int nt = 0; nt < 4; ++nt) {
        const bf16x8 b3f0 = *(const bf16x8*)&w3t[(nt * 16 + l16) * 72 + 0 * 32 + quad * 8];
        const bf16x8 b3f1 = *(const bf16x8*)&w3t[(nt * 16 + l16) * 72 + 1 * 32 + quad * 8];
#pragma unroll
        for (int mt = 0; mt < 4; ++mt) {
            f32x4 acc = __builtin_amdgcn_mfma_f32_16x16x32_bf16(a3[mt][0], b3f0, zero, 0, 0, 0);
            c3[nt][mt] = __builtin_amdgcn_mfma_f32_16x16x32_bf16(a3[mt][1], b3f1, acc, 0, 0, 0);
        }
    }

    // ---- feat multiply + max-pool over the 16 rows of each m-tile ----
#pragma unroll
    for (int mt = 0; mt < 4; ++mt) {
        const int qg = (rowbase >> 4) + mt;     // m-tile == one query
        int jrow[4];
#pragma unroll
        for (int r = 0; r < 4; ++r) jrow[r] = idx[rowbase + mt * 16 + quad * 4 + r];
#pragma unroll
        for (int nt = 0; nt < 4; ++nt) {
            const int col = nt * 16 + l16;
            float mx = -1e30f;
#pragma unroll
            for (int r = 0; r < 4; ++r) {
                const int j = jrow[r];
                float fv;
                if (col < NC) fv = xb[(size_t)j * NC + col];
                else          fv = ((const float*)&pb[j])[col - NC];
                mx = fmaxf(mx, fv * (c3[nt][mt][r] + b3v[nt]));
            }
            mx = fmaxf(mx, __shfl_xor(mx, 16, 64));
            mx = fmaxf(mx, __shfl_xor(mx, 32, 64));
            mx = fmaxf(mx, 0.f);                // relu AFTER pool
            if (quad == 0) pooled[(size_t)qg * 64 + col] = mx;
        }
    }
}

// ---------------------------------------------------------------------------
// Kernel 3: y1 = pooled(16384x64) @ fw1(64x128) + fb1 ; accumulate sum/sumsq.
// ---------------------------------------------------------------------------
__global__ __launch_bounds__(256) void gemm1_kernel(
    const float* __restrict__ A, const float* __restrict__ W,
    const float* __restrict__ bias, float* __restrict__ y,
    float* __restrict__ sum, float* __restrict__ sumsq) {
    __shared__ float As[64 * 64];
    __shared__ float Bs[64 * 128];
    const int t = threadIdx.x;
    const int r0 = blockIdx.x * 64;
    for (int i = t; i < 64 * 128; i += 256) Bs[i] = W[i];
    for (int i = t; i < 64 * 64; i += 256)  As[i] = A[(size_t)r0 * 64 + i];
    __syncthreads();

    const int c = t & 127, rg = t >> 7;
    float acc[32];
    const float bv = bias[c];
#pragma unroll
    for (int r = 0; r < 32; ++r) acc[r] = bv;

    for (int kk = 0; kk < 64; kk += 4) {
        const float b0 = Bs[(kk + 0) * 128 + c];
        const float b1 = Bs[(kk + 1) * 128 + c];
        const float b2 = Bs[(kk + 2) * 128 + c];
        const float b3 = Bs[(kk + 3) * 128 + c];
#pragma unroll
        for (int r = 0; r < 32; ++r) {
            const float4 a = *(const float4*)&As[(rg * 32 + r) * 64 + kk];
            acc[r] += a.x * b0 + a.y * b1 + a.z * b2 + a.w * b3;
        }
    }

    float s = 0.f, s2 = 0.f;
#pragma unroll
    for (int r = 0; r < 32; ++r) {
        const float v = acc[r];
        s += v; s2 += v * v;
        y[(size_t)(r0 + rg * 32 + r) * 128 + c] = v;
    }
    __syncthreads();
    As[t] = s; As[256 + t] = s2;
    __syncthreads();
    if (rg == 0) {
        atomicAdd(&sum[c],   As[c] + As[128 + c]);
        atomicAdd(&sumsq[c], As[256 + c] + As[256 + 128 + c]);
    }
}

// ---------------------------------------------------------------------------
// Kernel 4: h1 = relu(bn1(y1)); y2 = h1 @ fw2(128x128) + fb2 ; sum/sumsq.
// ---------------------------------------------------------------------------
__global__ __launch_bounds__(256) void gemm2_kernel(
    const float* __restrict__ y1, const float* __restrict__ W,
    const float* __restrict__ bias,
    const float* __restrict__ sum1, const float* __restrict__ sumsq1,
    const float* __restrict__ g1, const float* __restrict__ b1,
    float* __restrict__ y2, float* __restrict__ sum2, float* __restrict__ sumsq2) {
    __shared__ float As[64 * 128];
    __shared__ float Bs[64 * 128];
    __shared__ float a1s[128], s1s[128];
    const int t = threadIdx.x;
    const int r0 = blockIdx.x * 64;

    if (t < 128) {
        const float m = sum1[t] * INV_ROWS;
        const float v = sumsq1[t] * INV_ROWS - m * m;
        const float a = rsqrtf(v + BN_EPS) * g1[t];
        a1s[t] = a; s1s[t] = b1[t] - m * a;
    }
    for (int i = t; i < 64 * 128; i += 256) Bs[i] = W[i];
    __syncthreads();
    for (int i = t; i < 64 * 128; i += 256) {
        const int cc = i & 127;
        const float v = y1[(size_t)r0 * 128 + i];
        As[i] = fmaxf(v * a1s[cc] + s1s[cc], 0.f);
    }
    __syncthreads();

    const int c = t & 127, rg = t >> 7;
    float acc[32];
    const float bv = bias[c];
#pragma unroll
    for (int r = 0; r < 32; ++r) acc[r] = bv;

    for (int kk = 0; kk < 64; kk += 4) {
        const float b0 = Bs[(kk + 0) * 128 + c];
        const float b1v = Bs[(kk + 1) * 128 + c];
        const float b2 = Bs[(kk + 2) * 128 + c];
        const float b3 = Bs[(kk + 3) * 128 + c];
#pragma unroll
        for (int r = 0; r < 32; ++r) {
            const float4 a = *(const float4*)&As[(rg * 32 + r) * 128 + kk];
            acc[r] += a.x * b0 + a.y * b1v + a.z * b2 + a.w * b3;
        }
    }
    __syncthreads();
    for (int i = t; i < 64 * 128; i += 256) Bs[i] = W[64 * 128 + i];
    __syncthreads();
    for (int kk = 0; kk < 64; kk += 4) {
        const float b0 = Bs[(kk + 0) * 128 + c];
        const float b1v = Bs[(kk + 1) * 128 + c];
        const float b2 = Bs[(kk + 2) * 128 + c];
        const float b3 = Bs[(kk + 3) * 128 + c];
#pragma unroll
        for (int r = 0; r < 32; ++r) {
            const float4 a = *(const float4*)&As[(rg * 32 + r) * 128 + 64 + kk];
            acc[r] += a.x * b0 + a.y * b1v + a.z * b2 + a.w * b3;
        }
    }

    float s = 0.f, s2 = 0.f;
#pragma unroll
    for (int r = 0; r < 32; ++r) {
        const float v = acc[r];
        s += v; s2 += v * v;
        y2[(size_t)(r0 + rg * 32 + r) * 128 + c] = v;
    }
    __syncthreads();
    As[t] = s; As[256 + t] = s2;
    __syncthreads();
    if (rg == 0) {
        atomicAdd(&sum2[c],   As[c] + As[128 + c]);
        atomicAdd(&sumsq2[c], As[256 + c] + As[256 + 128 + c]);
    }
}

// ---------------------------------------------------------------------------
// Kernel 5: out = bn2(y2)
// ---------------------------------------------------------------------------
__global__ __launch_bounds__(256) void bnout_kernel(
    const float* __restrict__ y2, const float* __restrict__ sum2,
    const float* __restrict__ sumsq2, const float* __restrict__ g2,
    const float* __restrict__ b2, float* __restrict__ out) {
    const int i = blockIdx.x * 256 + threadIdx.x;
    const int c = i & 127;
    const float m = sum2[c] * INV_ROWS;
    const float v = sumsq2[c] * INV_ROWS - m * m;
    const float a = rsqrtf(v + BN_EPS) * g2[c];
    out[i] = y2[i] * a + (b2[c] - m * a);
}

extern "C" void kernel_launch(void* const* d_in, const int* in_sizes, int n_in,
                              void* d_out, int out_size, void* d_ws, size_t ws_size,
                              hipStream_t stream) {
    const float* x   = (const float*)d_in[0];
    const float* pos = (const float*)d_in[1];
    const float* rw1 = (const float*)d_in[2];
    const float* rb1 = (const float*)d_in[3];
    const float* rw2 = (const float*)d_in[4];
    const float* rb2 = (const float*)d_in[5];
    const float* rw3 = (const float*)d_in[6];
    const float* rb3 = (const float*)d_in[7];
    const float* fw1 = (const float*)d_in[8];
    const float* fb1 = (const float*)d_in[9];
    const float* g1  = (const float*)d_in[10];
    const float* b1  = (const float*)d_in[11];
    const float* fw2 = (const float*)d_in[12];
    const float* fb2 = (const float*)d_in[13];
    const float* g2  = (const float*)d_in[14];
    const float* b2  = (const float*)d_in[15];
    float* out = (float*)d_out;

    char* ws = (char*)d_ws;
    int*    idx      = (int*)ws;                           // 1 MB
    float*  pooled   = (float*)(ws + (1u << 20));          // 4 MB
    float*  y1       = (float*)(ws + (5u << 20));          // 8 MB
    float*  y2       = (float*)(ws + (13u << 20));         // 8 MB
    float*  stats    = (float*)(ws + (21u << 20));         // zeroed block start
    float*  sum1 = stats, *sumsq1 = stats + 128, *sum2 = stats + 256, *sumsq2 = stats + 384;
    int*    counts   = (int*)(stats + 512);                // 4*512
    int*    fill     = counts + NB * NCELL;                // 4*512
    int*    flagcnt  = fill + NB * NCELL;                  // 1
    int*    cellStart= (int*)(ws + (21u << 20) + (20u << 10));  // 4*513 ints
    int*    cellOf   = (int*)(ws + (21u << 20) + (32u << 10));  // 16384 ints
    int*    flaglist = (int*)(ws + (21u << 20) + (96u << 10));  // 16384 ints
    float4* pos4     = (float4*)(ws + (22u << 20));        // 256 KB
    float4* spt      = (float4*)(ws + (22u << 20) + (256u << 10)); // 256 KB

    hipMemsetAsync(stats, 0, (512 + 2048 + 2048 + 1) * sizeof(float), stream);

    prep_kernel<<<64, 256, 0, stream>>>(pos, pos4, cellOf, counts);
    scan_kernel<<<NB, 512, 0, stream>>>(counts, cellStart);
    scatter_kernel<<<64, 256, 0, stream>>>(pos4, cellOf, cellStart, fill, spt);
    knn_kernel<<<512, 256, 0, stream>>>(pos4, spt, cellStart, idx, flagcnt, flaglist);
    knn_fallback<<<64, 256, 0, stream>>>(pos4, idx, flagcnt, flaglist);
    mlp_kernel<<<1024, 256, 0, stream>>>(pos4, x, idx, rw1, rb1, rw2, rb2, rw3, rb3, pooled);
    gemm1_kernel<<<256, 256, 0, stream>>>(pooled, fw1, fb1, y1, sum1, sumsq1);
    gemm2_kernel<<<256, 256, 0, stream>>>(y1, fw2, fb2, sum1, sumsq1, g1, b1, y2, sum2, sumsq2);
    bnout_kernel<<<NROWS * 128 / 256, 256, 0, stream>>>(y2, sum2, sumsq2, g2, b2, out);
}

// Round 9
// 257.260 us; speedup vs baseline: 1.8484x; 1.0132x over previous
//
#include <hip/hip_runtime.h>
#include <hip/hip_bf16.h>
#include <math.h>

#define NPTS   4096
#define NB     4
#define NC     61
#define NK     16
#define NROWS  16384           // NB*NPTS
#define BN_EPS 1e-5f
#define INV_ROWS (1.0f/16384.0f)

#define GRD    8
#define NCELL  512             // 8^3
#define CELLH  0.125f

typedef short bf16x8 __attribute__((ext_vector_type(8)));
typedef float f32x4  __attribute__((ext_vector_type(4)));

// ---------------------------------------------------------------------------
// Kernel 0: pack pos -> float4, compute cell id, histogram cells.
// ---------------------------------------------------------------------------
__global__ __launch_bounds__(256) void prep_kernel(const float* __restrict__ pos,
                                                   float4* __restrict__ pos4,
                                                   int* __restrict__ cellOf,
                                                   int* __restrict__ counts) {
    const int i = blockIdx.x * 256 + threadIdx.x;
    if (i >= NB * NPTS) return;
    const float px = pos[i * 3 + 0], py = pos[i * 3 + 1], pz = pos[i * 3 + 2];
    pos4[i] = make_float4(px, py, pz, 0.f);
    const int cx = min(GRD - 1, max(0, (int)(px * GRD)));   // *8 exact in fp32
    const int cy = min(GRD - 1, max(0, (int)(py * GRD)));
    const int cz = min(GRD - 1, max(0, (int)(pz * GRD)));
    const int cid = ((cz << 3) + cy) * GRD + cx;
    cellOf[i] = cid;
    atomicAdd(&counts[(i >> 12) * NCELL + cid], 1);
}

// ---------------------------------------------------------------------------
// Kernel 0a: pack feat rows: xpad[i][0..60]=x[i], [61..63]=pos[i] (aligned).
// ---------------------------------------------------------------------------
__global__ __launch_bounds__(256) void xpack_kernel(const float* __restrict__ x,
                                                    const float* __restrict__ pos,
                                                    float* __restrict__ xpad) {
    const int g = blockIdx.x * 256 + threadIdx.x;
    const int i = g >> 6, c = g & 63;
    xpad[g] = (c < NC) ? x[i * NC + c] : pos[i * 3 + (c - NC)];
}

// ---------------------------------------------------------------------------
// Kernel 0b: exclusive prefix sum per batch (512 cells). One block per batch.
// ---------------------------------------------------------------------------
__global__ __launch_bounds__(512) void scan_kernel(const int* __restrict__ counts,
                                                   int* __restrict__ cellStart) {
    __shared__ int s[NCELL];
    const int b = blockIdx.x, t = threadIdx.x;
    s[t] = counts[b * NCELL + t];
    __syncthreads();
    for (int off = 1; off < NCELL; off <<= 1) {
        const int v = (t >= off) ? s[t - off] : 0;
        __syncthreads();
        s[t] += v;
        __syncthreads();
    }
    cellStart[b * (NCELL + 1) + t + 1] = s[t];   // inclusive -> shifted = exclusive
    if (t == 0) cellStart[b * (NCELL + 1)] = 0;
}

// ---------------------------------------------------------------------------
// Kernel 0c: scatter points into cell-sorted order; w = batch-local index.
// ---------------------------------------------------------------------------
__global__ __launch_bounds__(256) void scatter_kernel(const float4* __restrict__ pos4,
                                                      const int* __restrict__ cellOf,
                                                      const int* __restrict__ cellStart,
                                                      int* __restrict__ fill,
                                                      float4* __restrict__ spt) {
    const int i = blockIdx.x * 256 + threadIdx.x;
    if (i >= NB * NPTS) return;
    const int b = i >> 12;
    const int cid = cellOf[i];
    const int dst = cellStart[b * (NCELL + 1) + cid] + atomicAdd(&fill[b * NCELL + cid], 1);
    float4 p = pos4[i];
    p.w = __int_as_float(i & 4095);
    spt[(b << 12) + dst] = p;
}

// ---------------------------------------------------------------------------
// Kernel 1: grid KNN (unchanged from round 7).
// ---------------------------------------------------------------------------
#define OCAP 8
#define NPAD 257

__global__ __launch_bounds__(256) void knn_kernel(const float4* __restrict__ pos4,
                                                  const float4* __restrict__ spt,
                                                  const int* __restrict__ cellStart,
                                                  int* __restrict__ idx_out,
                                                  int* __restrict__ flagcnt,
                                                  int* __restrict__ flaglist) {
    __shared__ unsigned long long buf[OCAP * NPAD];   // 16.4 KB
    const int t  = threadIdx.x;
    const int l8 = t & 7;
    const int q  = blockIdx.x * 32 + (t >> 3);        // global query row
    const int b  = q >> 12;
    const float4* __restrict__ sb = spt + (b << 12);
    const int* __restrict__ cs = cellStart + b * (NCELL + 1);

    const float4 qp = pos4[q];
    const float qx = qp.x, qy = qp.y, qz = qp.z;
    const int cx = min(GRD - 1, max(0, (int)(qx * GRD)));
    const int cy = min(GRD - 1, max(0, (int)(qy * GRD)));
    const int cz = min(GRD - 1, max(0, (int)(qz * GRD)));
    const int x0 = max(0, cx - 1), x1 = min(GRD - 1, cx + 1);

    unsigned long long bk[16];
#pragma unroll
    for (int i = 0; i < 16; ++i) bk[i] = ~0ull;
    unsigned int thr_bits = 0xFFFFFFFFu;
    int owptr = 0;

    auto compact = [&]() {
        unsigned long long od[OCAP];
#pragma unroll
        for (int s = 0; s < OCAP; ++s) {
            const unsigned long long v = buf[s * NPAD + t];
            od[s] = (s < owptr) ? v : ~0ull;
        }
        owptr = 0;
#pragma unroll
        for (int k = 2; k <= 8; k <<= 1) {
#pragma unroll
            for (int j = k >> 1; j > 0; j >>= 1) {
#pragma unroll
                for (int i = 0; i < 8; ++i) {
                    const int l = i ^ j;
                    if (l > i) {
                        const bool up = ((i & k) == 0);
                        const unsigned long long a = od[i], c = od[l];
                        const bool sw = up ? (c < a) : (a < c);
                        od[i] = sw ? c : a;
                        od[l] = sw ? a : c;
                    }
                }
            }
        }
#pragma unroll
        for (int i = 8; i < 16; ++i) {
            const unsigned long long c = od[15 - i];
            bk[i] = (c < bk[i]) ? c : bk[i];
        }
#pragma unroll
        for (int j = 8; j > 0; j >>= 1) {
#pragma unroll
            for (int i = 0; i < 16; ++i) {
                const int l = i ^ j;
                if (l > i) {
                    const unsigned long long a = bk[i], c = bk[l];
                    const bool sw = (c < a);
                    bk[i] = sw ? c : a;
                    bk[l] = sw ? a : c;
                }
            }
        }
        unsigned int th = (unsigned int)(bk[15] >> 32);
#pragma unroll
        for (int m = 1; m <= 4; m <<= 1) {
            const unsigned int o = __shfl_xor(th, m, 8);
            th = (o < th) ? o : th;
        }
        thr_bits = th;
    };

    for (int rz = 0; rz < 3; ++rz) {
        for (int ry = 0; ry < 3; ++ry) {
            const int zz = cz + rz - 1, yy = cy + ry - 1;
            int rs = 0, re = 0;
            if (zz >= 0 && zz < GRD && yy >= 0 && yy < GRD) {
                const int rowb = ((zz << 3) + yy) << 3;
                rs = cs[rowb + x0];
                re = cs[rowb + x1 + 1];
            }
            int p = rs + l8;
            while (__any(p < re)) {
                if (p < re) {
                    const float4 c = sb[p];
                    const float dx = qx - c.x, dy = qy - c.y, dz = qz - c.z;
                    const float d2 = __fadd_rn(__fadd_rn(__fmul_rn(dx, dx), __fmul_rn(dy, dy)),
                                               __fmul_rn(dz, dz));
                    if (__float_as_uint(d2) < thr_bits) {
                        buf[owptr * NPAD + t] =
                            ((unsigned long long)__float_as_uint(d2) << 32) |
                            (unsigned int)__float_as_int(c.w);
                        owptr++;
                    }
                }
                p += 8;
                if (__any(owptr >= OCAP - 1)) compact();
            }
        }
    }
    compact();

#pragma unroll
    for (int m = 1; m <= 4; m <<= 1) {
        unsigned long long ot[16];
#pragma unroll
        for (int i = 0; i < 16; ++i) ot[i] = __shfl_xor(bk[i], m, 8);
#pragma unroll
        for (int i = 0; i < 16; ++i) {
            const unsigned long long c = ot[15 - i];
            bk[i] = (c < bk[i]) ? c : bk[i];
        }
#pragma unroll
        for (int j = 8; j > 0; j >>= 1) {
#pragma unroll
            for (int i = 0; i < 16; ++i) {
                const int l = i ^ j;
                if (l > i) {
                    const unsigned long long a = bk[i], c = bk[l];
                    const bool sw = (c < a);
                    bk[i] = sw ? c : a;
                    bk[l] = sw ? a : c;
                }
            }
        }
    }

    if (l8 == 0) {
        const int ob = q * NK;
        *(int4*)&idx_out[ob + 0]  = make_int4((int)bk[0],  (int)bk[1],  (int)bk[2],  (int)bk[3]);
        *(int4*)&idx_out[ob + 4]  = make_int4((int)bk[4],  (int)bk[5],  (int)bk[6],  (int)bk[7]);
        *(int4*)&idx_out[ob + 8]  = make_int4((int)bk[8],  (int)bk[9],  (int)bk[10], (int)bk[11]);
        *(int4*)&idx_out[ob + 12] = make_int4((int)bk[12], (int)bk[13], (int)bk[14], (int)bk[15]);

        const int y0 = max(0, cy - 1), y1 = min(GRD - 1, cy + 1);
        const int z0 = max(0, cz - 1), z1 = min(GRD - 1, cz + 1);
        float mg = 1e30f;
        if (x0 > 0)       mg = fminf(mg, qx - x0 * CELLH);
        if (x1 < GRD - 1) mg = fminf(mg, (x1 + 1) * CELLH - qx);
        if (y0 > 0)       mg = fminf(mg, qy - y0 * CELLH);
        if (y1 < GRD - 1) mg = fminf(mg, (y1 + 1) * CELLH - qy);
        if (z0 > 0)       mg = fminf(mg, qz - z0 * CELLH);
        if (z1 < GRD - 1) mg = fminf(mg, (z1 + 1) * CELLH - qz);
        mg = fmaxf(mg - 1e-5f, 0.f);
        const float mg2 = mg * mg;
        if ((unsigned int)(bk[15] >> 32) >= __float_as_uint(mg2)) {
            const int slot = atomicAdd(flagcnt, 1);
            flaglist[slot] = q;
        }
    }
}

// ---------------------------------------------------------------------------
// Kernel 1b: brute-force fallback, one block per flagged query (round 7).
// ---------------------------------------------------------------------------
__global__ __launch_bounds__(256) void knn_fallback(const float4* __restrict__ pos4,
                                                    int* __restrict__ idx_out,
                                                    const int* __restrict__ flagcnt,
                                                    const int* __restrict__ flaglist) {
    __shared__ unsigned long long wres[4 * 16];
    const int nf = flagcnt[0];
    const int t = threadIdx.x;
    const int w = t >> 6;

    for (int fi = blockIdx.x; fi < nf; fi += 64) {
        const int qi = flaglist[fi];
        const int b = qi >> 12;
        const float4* __restrict__ pb = pos4 + (b << 12);
        const float4 qp = pb[qi & 4095];

        float4 c[16];
#pragma unroll
        for (int s = 0; s < 16; ++s) c[s] = pb[(s << 8) | t];

        unsigned long long key[16];
#pragma unroll
        for (int s = 0; s < 16; ++s) {
            const int j = (s << 8) | t;
            const float dx = qp.x - c[s].x, dy = qp.y - c[s].y, dz = qp.z - c[s].z;
            const float d2 = __fadd_rn(__fadd_rn(__fmul_rn(dx, dx), __fmul_rn(dy, dy)),
                                       __fmul_rn(dz, dz));
            key[s] = ((unsigned long long)__float_as_uint(d2) << 32) | (unsigned int)j;
        }

#pragma unroll
        for (int k = 2; k <= 16; k <<= 1) {
#pragma unroll
            for (int j = k >> 1; j > 0; j >>= 1) {
#pragma unroll
                for (int i = 0; i < 16; ++i) {
                    const int l = i ^ j;
                    if (l > i) {
                        const bool up = ((i & k) == 0);
                        const unsigned long long a = key[i], cc = key[l];
                        const bool sw = up ? (cc < a) : (a < cc);
                        key[i] = sw ? cc : a;
                        key[l] = sw ? a : cc;
                    }
                }
            }
        }

#pragma unroll
        for (int m = 1; m <= 32; m <<= 1) {
            unsigned long long ot[16];
#pragma unroll
            for (int i = 0; i < 16; ++i) ot[i] = __shfl_xor(key[i], m, 64);
#pragma unroll
            for (int i = 0; i < 16; ++i) {
                const unsigned long long cc = ot[15 - i];
                key[i] = (cc < key[i]) ? cc : key[i];
            }
#pragma unroll
            for (int j = 8; j > 0; j >>= 1) {
#pragma unroll
                for (int i = 0; i < 16; ++i) {
                    const int l = i ^ j;
                    if (l > i) {
                        const unsigned long long a = key[i], cc = key[l];
                        const bool sw = (cc < a);
                        key[i] = sw ? cc : a;
                        key[l] = sw ? a : cc;
                    }
                }
            }
        }

        if ((t & 63) == 0) {
#pragma unroll
            for (int i = 0; i < 16; ++i) wres[w * 16 + i] = key[i];
        }
        __syncthreads();

        if (t == 0) {
            int hp[4] = {0, 0, 0, 0};
            const int ob = qi * NK;
            for (int o = 0; o < NK; ++o) {
                unsigned long long bestk = ~0ull;
                int bestw = 0;
#pragma unroll
                for (int w2 = 0; w2 < 4; ++w2) {
                    const unsigned long long h = (hp[w2] < 16) ? wres[w2 * 16 + hp[w2]] : ~0ull;
                    if (h < bestk) { bestk = h; bestw = w2; }
                }
                idx_out[ob + o] = (int)(bestk & 0xFFFFFFFFu);
                hp[bestw]++;
            }
        }
        __syncthreads();
    }
}

// ---------------------------------------------------------------------------
// Kernel 2: relation MLP via MFMA (16x16x32 bf16).
// Round-9 deltas: w1t dropped from LDS (layer-1 B-frag built once from
// global; LDS 53.8 -> 51.3 KB => 3 blocks/CU instead of 2); feat gathered
// from xpad (64-col aligned rows, no divergent 61..63 tail).
// Layouts (verified): A[m=lane&15][k=quad*8+j], B[k=quad*8+j][n=lane&15],
// C[row=quad*4+reg][col=lane&15].
// ---------------------------------------------------------------------------
__device__ __forceinline__ unsigned int f2bf(float f) {   // RNE to bf16 bits
    unsigned int b = __float_as_uint(f);
    return (b + 0x7FFFu + ((b >> 16) & 1u)) >> 16;
}

__global__ __launch_bounds__(256) void mlp_kernel(
    const float4* __restrict__ pos4, const float* __restrict__ xpad,
    const int* __restrict__ idx,
    const float* __restrict__ rw1, const float* __restrict__ rb1,
    const float* __restrict__ rw2, const float* __restrict__ rb2,
    const float* __restrict__ rw3, const float* __restrict__ rb3,
    float* __restrict__ pooled) {
    __shared__ __attribute__((aligned(16))) unsigned short w2t[64 * 40];  // [n][k]
    __shared__ __attribute__((aligned(16))) unsigned short w3t[64 * 72];  // [n][k]
    __shared__ __attribute__((aligned(16))) unsigned short scr[4 * 64 * 72]; // per-wave

    const int t = threadIdx.x;
    for (int i = t; i < 64 * 32; i += 256) {
        const int n = i >> 5, k = i & 31;
        w2t[n * 40 + k] = (unsigned short)f2bf(rw2[k * 64 + n]);
    }
    for (int i = t; i < 64 * 64; i += 256) {
        const int n = i >> 6, k = i & 63;
        w3t[n * 72 + k] = (unsigned short)f2bf(rw3[k * 64 + n]);
    }
    __syncthreads();

    const int lane = t & 63;
    const int quad = lane >> 4;
    const int l16  = lane & 15;
    unsigned short* __restrict__ ws = &scr[(t >> 6) * 64 * 72];

    const int rowbase = blockIdx.x * 256 + (t & 192);   // (t>>6)*64
    const int b = rowbase >> 16;                        // 65536 items per batch
    const float4* __restrict__ pb = pos4 + ((size_t)b << 12);
    const float* __restrict__ xpb = xpad + (((size_t)b << 12) << 6);

    // layer-1 B fragment straight from global (once): k=quad*8+j
    bf16x8 b1f[2];
#pragma unroll
    for (int nt = 0; nt < 2; ++nt) {
        const int n = nt * 16 + l16;
#pragma unroll
        for (int j = 0; j < 8; ++j) {
            const int k = quad * 8 + j;
            float f = 0.f;
            if (k < 10) f = rw1[k * 32 + n];
            else if (k == 15) f = rb1[n];
            b1f[nt][j] = (short)f2bf(f);
        }
    }

    // ---- build rin rows (one per lane), bf16, stride 40; k15 = 1.0 ----
    {
        const int row_g = rowbase + lane;
        const int q = row_g >> 4;
        const int j = idx[row_g];
        const float4 cp = pb[q & 4095];
        const float4 gp = pb[j];
        const float rx = gp.x - cp.x, ry = gp.y - cp.y, rz = gp.z - cp.z;
        const float ss = rx * rx + ry * ry + rz * rz;
        const float dis = (ss > 0.f) ? sqrtf(ss) : 0.f;
        unsigned int d[20];
#pragma unroll
        for (int i = 0; i < 20; ++i) d[i] = 0;
        d[0] = f2bf(cp.x) | (f2bf(cp.y) << 16);
        d[1] = f2bf(cp.z) | (f2bf(gp.x) << 16);
        d[2] = f2bf(gp.y) | (f2bf(gp.z) << 16);
        d[3] = f2bf(rx)   | (f2bf(ry) << 16);
        d[4] = f2bf(rz)   | (f2bf(dis) << 16);
        d[7] = 0x3F800000u;   // k14=0, k15=1.0 (bias slot)
        unsigned int* wr = (unsigned int*)&ws[lane * 40];
#pragma unroll
        for (int i = 0; i < 20; ++i) wr[i] = d[i];
    }
    __builtin_amdgcn_s_waitcnt(0);   // lgkm drain before same-wave read-back

    const f32x4 zero = {0.f, 0.f, 0.f, 0.f};

    // ---- layer 1: 64x32 = A(64x32) @ w1(32x32-padded) ----
    bf16x8 a1[4];
#pragma unroll
    for (int mt = 0; mt < 4; ++mt)
        a1[mt] = *(const bf16x8*)&ws[(mt * 16 + l16) * 40 + quad * 8];

    f32x4 c1[2][4];
#pragma unroll
    for (int nt = 0; nt < 2; ++nt)
#pragma unroll
        for (int mt = 0; mt < 4; ++mt)
            c1[nt][mt] = __builtin_amdgcn_mfma_f32_16x16x32_bf16(a1[mt], b1f[nt], zero, 0, 0, 0);

    // relu -> h1 to LDS (stride 40)
#pragma unroll
    for (int nt = 0; nt < 2; ++nt)
#pragma unroll
        for (int mt = 0; mt < 4; ++mt)
#pragma unroll
            for (int r = 0; r < 4; ++r)
                ws[(mt * 16 + quad * 4 + r) * 40 + nt * 16 + l16] =
                    (unsigned short)f2bf(fmaxf(c1[nt][mt][r], 0.f));
    __builtin_amdgcn_s_waitcnt(0);

    // ---- layer 2: 64x64 = h1(64x32) @ w2(32x64) ----
    float b2v[4], b3v[4];
#pragma unroll
    for (int nt = 0; nt < 4; ++nt) { b2v[nt] = rb2[nt * 16 + l16]; b3v[nt] = rb3[nt * 16 + l16]; }

    bf16x8 a2[4];
#pragma unroll
    for (int mt = 0; mt < 4; ++mt)
        a2[mt] = *(const bf16x8*)&ws[(mt * 16 + l16) * 40 + quad * 8];

    f32x4 c2[4][4];
#pragma unroll
    for (int nt = 0; nt < 4; ++nt) {
        const bf16x8 b2f = *(const bf16x8*)&w2t[(nt * 16 + l16) * 40 + quad * 8];
#pragma unroll
        for (int mt = 0; mt < 4; ++mt)
            c2[nt][mt] = __builtin_amdgcn_mfma_f32_16x16x32_bf16(a2[mt], b2f, zero, 0, 0, 0);
    }

    // bias + relu -> h2 to LDS (stride 72)
#pragma unroll
    for (int nt = 0; nt < 4; ++nt)
#pragma unroll
        for (int mt = 0; mt < 4; ++mt)
#pragma unroll
            for (int r = 0; r < 4; ++r)
                ws[(mt * 16 + quad * 4 + r) * 72 + nt * 16 + l16] =
                    (unsigned short)f2bf(fmaxf(c2[nt][mt][r] + b2v[nt], 0.f));
    __builtin_amdgcn_s_waitcnt(0);

    // ---- layer 3: 64x64 = h2(64x64) @ w3(64x64), 2 k-tiles ----
    bf16x8 a3[4][2];
#pragma unroll
    for (int mt = 0; mt < 4; ++mt)
#pragma unroll
        for (int kt = 0; kt < 2; ++kt)
            a3[mt][kt] = *(const bf16x8*)&ws[(mt * 16 + l16) * 72 + kt * 32 + quad * 8];

    f32x4 c3[4][4];
#pragma unroll
    for (int nt = 0; nt < 4; ++nt) {
        const bf16x8 b3f0 = *(const bf16x8*)&w3t[(nt * 16 + l16) * 72 + 0 * 32 + quad * 8];
        const bf16x8 b3f1 = *(const bf16x8*)&w3t[(nt * 16 + l16) * 72 + 1 * 32 + quad * 8];
#pragma unroll
        for (int mt = 0; mt < 4; ++mt) {
            f32x4 acc = __builtin_amdgcn_mfma_f32_16x16x32_bf16(a3[mt][0], b3f0, zero, 0, 0, 0);
            c3[nt][mt] = __builtin_amdgcn_mfma_f32_16x16x32_bf16(a3[mt][1], b3f1, acc, 0, 0, 0);
        }
    }

    // ---- feat multiply + max-pool over the 16 rows of each m-tile ----
#pragma unroll
    for (int mt = 0; mt < 4; ++mt) {
        const int qg = (rowbase >> 4) + mt;     // m-tile == one query
        int jrow[4];
#pragma unroll
        for (int r = 0; r < 4; ++r) jrow[r] = idx[rowbase + mt * 16 + quad * 4 + r];
#pragma unroll
        for (int nt = 0; nt < 4; ++nt) {
            const int col = nt * 16 + l16;
            float mx = -1e30f;
#pragma unroll
            for (int r = 0; r < 4; ++r) {
                const float fv = xpb[((size_t)jrow[r] << 6) + col];
                mx = fmaxf(mx, fv * (c3[nt][mt][r] + b3v[nt]));
            }
            mx = fmaxf(mx, __shfl_xor(mx, 16, 64));
            mx = fmaxf(mx, __shfl_xor(mx, 32, 64));
            mx = fmaxf(mx, 0.f);                // relu AFTER pool
            if (quad == 0) pooled[(size_t)qg * 64 + col] = mx;
        }
    }
}

// ---------------------------------------------------------------------------
// Kernel 3: y1 = pooled(16384x64) @ fw1(64x128) + fb1 ; accumulate sum/sumsq.
// Round 9: 512 blocks x 32-row tiles (was 256 x 64) -> 2+ blocks/CU.
// ---------------------------------------------------------------------------
__global__ __launch_bounds__(256) void gemm1_kernel(
    const float* __restrict__ A, const float* __restrict__ W,
    const float* __restrict__ bias, float* __restrict__ y,
    float* __restrict__ sum, float* __restrict__ sumsq) {
    __shared__ float As[32 * 64];
    __shared__ float Bs[64 * 128];
    const int t = threadIdx.x;
    const int r0 = blockIdx.x * 32;
    for (int i = t; i < 64 * 128; i += 256) Bs[i] = W[i];
    for (int i = t; i < 32 * 64; i += 256)  As[i] = A[(size_t)r0 * 64 + i];
    __syncthreads();

    const int c = t & 127, rg = t >> 7;
    float acc[16];
    const float bv = bias[c];
#pragma unroll
    for (int r = 0; r < 16; ++r) acc[r] = bv;

    for (int kk = 0; kk < 64; kk += 4) {
        const float b0 = Bs[(kk + 0) * 128 + c];
        const float b1 = Bs[(kk + 1) * 128 + c];
        const float b2 = Bs[(kk + 2) * 128 + c];
        const float b3 = Bs[(kk + 3) * 128 + c];
#pragma unroll
        for (int r = 0; r < 16; ++r) {
            const float4 a = *(const float4*)&As[(rg * 16 + r) * 64 + kk];
            acc[r] += a.x * b0 + a.y * b1 + a.z * b2 + a.w * b3;
        }
    }

    float s = 0.f, s2 = 0.f;
#pragma unroll
    for (int r = 0; r < 16; ++r) {
        const float v = acc[r];
        s += v; s2 += v * v;
        y[(size_t)(r0 + rg * 16 + r) * 128 + c] = v;
    }
    __syncthreads();
    As[t] = s; As[256 + t] = s2;
    __syncthreads();
    if (rg == 0) {
        atomicAdd(&sum[c],   As[c] + As[128 + c]);
        atomicAdd(&sumsq[c], As[256 + c] + As[256 + 128 + c]);
    }
}

// ---------------------------------------------------------------------------
// Kernel 4: h1 = relu(bn1(y1)); y2 = h1 @ fw2(128x128) + fb2 ; sum/sumsq.
// Round 9: 512 blocks x 32-row tiles (was 256 x 64).
// ---------------------------------------------------------------------------
__global__ __launch_bounds__(256) void gemm2_kernel(
    const float* __restrict__ y1, const float* __restrict__ W,
    const float* __restrict__ bias,
    const float* __restrict__ sum1, const float* __restrict__ sumsq1,
    const float* __restrict__ g1, const float* __restrict__ b1,
    float* __restrict__ y2, float* __restrict__ sum2, float* __restrict__ sumsq2) {
    __shared__ float As[32 * 128];
    __shared__ float Bs[64 * 128];
    __shared__ float a1s[128], s1s[128];
    const int t = threadIdx.x;
    const int r0 = blockIdx.x * 32;

    if (t < 128) {
        const float m = sum1[t] * INV_ROWS;
        const float v = sumsq1[t] * INV_ROWS - m * m;
        const float a = rsqrtf(v + BN_EPS) * g1[t];
        a1s[t] = a; s1s[t] = b1[t] - m * a;
    }
    for (int i = t; i < 64 * 128; i += 256) Bs[i] = W[i];
    __syncthreads();
    for (int i = t; i < 32 * 128; i += 256) {
        const int cc = i & 127;
        const float v = y1[(size_t)r0 * 128 + i];
        As[i] = fmaxf(v * a1s[cc] + s1s[cc], 0.f);
    }
    __syncthreads();

    const int c = t & 127, rg = t >> 7;
    float acc[16];
    const float bv = bias[c];
#pragma unroll
    for (int r = 0; r < 16; ++r) acc[r] = bv;

    for (int kk = 0; kk < 64; kk += 4) {
        const float b0 = Bs[(kk + 0) * 128 + c];
        const float b1v = Bs[(kk + 1) * 128 + c];
        const float b2 = Bs[(kk + 2) * 128 + c];
        const float b3 = Bs[(kk + 3) * 128 + c];
#pragma unroll
        for (int r = 0; r < 16; ++r) {
            const float4 a = *(const float4*)&As[(rg * 16 + r) * 128 + kk];
            acc[r] += a.x * b0 + a.y * b1v + a.z * b2 + a.w * b3;
        }
    }
    __syncthreads();
    for (int i = t; i < 64 * 128; i += 256) Bs[i] = W[64 * 128 + i];
    __syncthreads();
    for (int kk = 0; kk < 64; kk += 4) {
        const float b0 = Bs[(kk + 0) * 128 + c];
        const float b1v = Bs[(kk + 1) * 128 + c];
        const float b2 = Bs[(kk + 2) * 128 + c];
        const float b3 = Bs[(kk + 3) * 128 + c];
#pragma unroll
        for (int r = 0; r < 16; ++r) {
            const float4 a = *(const float4*)&As[(rg * 16 + r) * 128 + 64 + kk];
            acc[r] += a.x * b0 + a.y * b1v + a.z * b2 + a.w * b3;
        }
    }

    float s = 0.f, s2 = 0.f;
#pragma unroll
    for (int r = 0; r < 16; ++r) {
        const float v = acc[r];
        s += v; s2 += v * v;
        y2[(size_t)(r0 + rg * 16 + r) * 128 + c] = v;
    }
    __syncthreads();
    As[t] = s; As[256 + t] = s2;
    __syncthreads();
    if (rg == 0) {
        atomicAdd(&sum2[c],   As[c] + As[128 + c]);
        atomicAdd(&sumsq2[c], As[256 + c] + As[256 + 128 + c]);
    }
}

// ---------------------------------------------------------------------------
// Kernel 5: out = bn2(y2)
// ---------------------------------------------------------------------------
__global__ __launch_bounds__(256) void bnout_kernel(
    const float* __restrict__ y2, const float* __restrict__ sum2,
    const float* __restrict__ sumsq2, const float* __restrict__ g2,
    const float* __restrict__ b2, float* __restrict__ out) {
    const int i = blockIdx.x * 256 + threadIdx.x;
    const int c = i & 127;
    const float m = sum2[c] * INV_ROWS;
    const float v = sumsq2[c] * INV_ROWS - m * m;
    const float a = rsqrtf(v + BN_EPS) * g2[c];
    out[i] = y2[i] * a + (b2[c] - m * a);
}

extern "C" void kernel_launch(void* const* d_in, const int* in_sizes, int n_in,
                              void* d_out, int out_size, void* d_ws, size_t ws_size,
                              hipStream_t stream) {
    const float* x   = (const float*)d_in[0];
    const float* pos = (const float*)d_in[1];
    const float* rw1 = (const float*)d_in[2];
    const float* rb1 = (const float*)d_in[3];
    const float* rw2 = (const float*)d_in[4];
    const float* rb2 = (const float*)d_in[5];
    const float* rw3 = (const float*)d_in[6];
    const float* rb3 = (const float*)d_in[7];
    const float* fw1 = (const float*)d_in[8];
    const float* fb1 = (const float*)d_in[9];
    const float* g1  = (const float*)d_in[10];
    const float* b1  = (const float*)d_in[11];
    const float* fw2 = (const float*)d_in[12];
    const float* fb2 = (const float*)d_in[13];
    const float* g2  = (const float*)d_in[14];
    const float* b2  = (const float*)d_in[15];
    float* out = (float*)d_out;

    char* ws = (char*)d_ws;
    int*    idx      = (int*)ws;                           // 1 MB
    float*  pooled   = (float*)(ws + (1u << 20));          // 4 MB
    float*  y1       = (float*)(ws + (5u << 20));          // 8 MB
    float*  y2       = (float*)(ws + (13u << 20));         // 8 MB
    float*  stats    = (float*)(ws + (21u << 20));         // zeroed block start
    float*  sum1 = stats, *sumsq1 = stats + 128, *sum2 = stats + 256, *sumsq2 = stats + 384;
    int*    counts   = (int*)(stats + 512);                // 4*512
    int*    fill     = counts + NB * NCELL;                // 4*512
    int*    flagcnt  = fill + NB * NCELL;                  // 1
    int*    cellStart= (int*)(ws + (21u << 20) + (20u << 10));  // 4*513 ints
    int*    cellOf   = (int*)(ws + (21u << 20) + (32u << 10));  // 16384 ints
    int*    flaglist = (int*)(ws + (21u << 20) + (96u << 10));  // 16384 ints
    float4* pos4     = (float4*)(ws + (22u << 20));        // 256 KB
    float4* spt      = (float4*)(ws + (22u << 20) + (256u << 10)); // 256 KB
    float*  xpad     = (float*)(ws + (23u << 20));         // 16384*64 f32 (4 MB)

    hipMemsetAsync(stats, 0, (512 + 2048 + 2048 + 1) * sizeof(float), stream);

    prep_kernel<<<64, 256, 0, stream>>>(pos, pos4, cellOf, counts);
    xpack_kernel<<<4096, 256, 0, stream>>>(x, pos, xpad);
    scan_kernel<<<NB, 512, 0, stream>>>(counts, cellStart);
    scatter_kernel<<<64, 256, 0, stream>>>(pos4, cellOf, cellStart, fill, spt);
    knn_kernel<<<512, 256, 0, stream>>>(pos4, spt, cellStart, idx, flagcnt, flaglist);
    knn_fallback<<<64, 256, 0, stream>>>(pos4, idx, flagcnt, flaglist);
    mlp_kernel<<<1024, 256, 0, stream>>>(pos4, xpad, idx, rw1, rb1, rw2, rb2, rw3, rb3, pooled);
    gemm1_kernel<<<512, 256, 0, stream>>>(pooled, fw1, fb1, y1, sum1, sumsq1);
    gemm2_kernel<<<512, 256, 0, stream>>>(y1, fw2, fb2, sum1, sumsq1, g1, b1, y2, sum2, sumsq2);
    bnout_kernel<<<NROWS * 128 / 256, 256, 0, stream>>>(y2, sum2, sumsq2, g2, b2, out);
}

// Round 10
// 257.169 us; speedup vs baseline: 1.8491x; 1.0004x over previous
//
#include <hip/hip_runtime.h>
#include <hip/hip_bf16.h>
#include <math.h>

#define NPTS   4096
#define NB     4
#define NC     61
#define NK     16
#define NROWS  16384           // NB*NPTS
#define BN_EPS 1e-5f
#define INV_ROWS (1.0f/16384.0f)

#define GRD    8
#define NCELL  512             // 8^3
#define CELLH  0.125f

typedef short bf16x8 __attribute__((ext_vector_type(8)));
typedef float f32x4  __attribute__((ext_vector_type(4)));

// ---------------------------------------------------------------------------
// Kernel 0 (fused): xpad pack (all 1M threads) + pos4/cell/histogram (first
// 16384 threads). xpad[i][0..60]=x[i], [61..63]=pos[i].
// ---------------------------------------------------------------------------
__global__ __launch_bounds__(256) void prep_kernel(const float* __restrict__ pos,
                                                   const float* __restrict__ x,
                                                   float4* __restrict__ pos4,
                                                   int* __restrict__ cellOf,
                                                   int* __restrict__ counts,
                                                   float* __restrict__ xpad) {
    const int g = blockIdx.x * 256 + threadIdx.x;       // 0 .. 1048575
    const int i = g >> 6, c = g & 63;
    xpad[g] = (c < NC) ? x[i * NC + c] : pos[i * 3 + (c - NC)];
    if (g < NB * NPTS) {
        const float px = pos[g * 3 + 0], py = pos[g * 3 + 1], pz = pos[g * 3 + 2];
        pos4[g] = make_float4(px, py, pz, 0.f);
        const int cx = min(GRD - 1, max(0, (int)(px * GRD)));   // *8 exact in fp32
        const int cy = min(GRD - 1, max(0, (int)(py * GRD)));
        const int cz = min(GRD - 1, max(0, (int)(pz * GRD)));
        const int cid = ((cz << 3) + cy) * GRD + cx;
        cellOf[g] = cid;
        atomicAdd(&counts[(g >> 12) * NCELL + cid], 1);
    }
}

// ---------------------------------------------------------------------------
// Kernel 0b: exclusive prefix sum per batch (512 cells). One block per batch.
// ---------------------------------------------------------------------------
__global__ __launch_bounds__(512) void scan_kernel(const int* __restrict__ counts,
                                                   int* __restrict__ cellStart) {
    __shared__ int s[NCELL];
    const int b = blockIdx.x, t = threadIdx.x;
    s[t] = counts[b * NCELL + t];
    __syncthreads();
    for (int off = 1; off < NCELL; off <<= 1) {
        const int v = (t >= off) ? s[t - off] : 0;
        __syncthreads();
        s[t] += v;
        __syncthreads();
    }
    cellStart[b * (NCELL + 1) + t + 1] = s[t];   // inclusive -> shifted = exclusive
    if (t == 0) cellStart[b * (NCELL + 1)] = 0;
}

// ---------------------------------------------------------------------------
// Kernel 0c: scatter points into cell-sorted order; w = batch-local index.
// ---------------------------------------------------------------------------
__global__ __launch_bounds__(256) void scatter_kernel(const float4* __restrict__ pos4,
                                                      const int* __restrict__ cellOf,
                                                      const int* __restrict__ cellStart,
                                                      int* __restrict__ fill,
                                                      float4* __restrict__ spt) {
    const int i = blockIdx.x * 256 + threadIdx.x;
    if (i >= NB * NPTS) return;
    const int b = i >> 12;
    const int cid = cellOf[i];
    const int dst = cellStart[b * (NCELL + 1) + cid] + atomicAdd(&fill[b * NCELL + cid], 1);
    float4 p = pos4[i];
    p.w = __int_as_float(i & 4095);
    spt[(b << 12) + dst] = p;
}

// ---------------------------------------------------------------------------
// Kernel 1: grid KNN. Round-10: 16 lanes/query (was 8), grid 1024 -> 4096
// waves = 16 waves/CU (2x occupancy); scan ~13 pts/lane; 4-round width-16
// cross-lane bitonic merge. Selection machinery unchanged.
// ---------------------------------------------------------------------------
#define OCAP 8
#define NPAD 257

__global__ __launch_bounds__(256) void knn_kernel(const float4* __restrict__ pos4,
                                                  const float4* __restrict__ spt,
                                                  const int* __restrict__ cellStart,
                                                  int* __restrict__ idx_out,
                                                  int* __restrict__ flagcnt,
                                                  int* __restrict__ flaglist) {
    __shared__ unsigned long long buf[OCAP * NPAD];   // 16.4 KB
    const int t   = threadIdx.x;
    const int l16 = t & 15;
    const int q   = blockIdx.x * 16 + (t >> 4);       // global query row
    const int b   = q >> 12;
    const float4* __restrict__ sb = spt + (b << 12);
    const int* __restrict__ cs = cellStart + b * (NCELL + 1);

    const float4 qp = pos4[q];
    const float qx = qp.x, qy = qp.y, qz = qp.z;
    const int cx = min(GRD - 1, max(0, (int)(qx * GRD)));
    const int cy = min(GRD - 1, max(0, (int)(qy * GRD)));
    const int cz = min(GRD - 1, max(0, (int)(qz * GRD)));
    const int x0 = max(0, cx - 1), x1 = min(GRD - 1, cx + 1);

    unsigned long long bk[16];
#pragma unroll
    for (int i = 0; i < 16; ++i) bk[i] = ~0ull;
    unsigned int thr_bits = 0xFFFFFFFFu;
    int owptr = 0;

    auto compact = [&]() {
        unsigned long long od[OCAP];
#pragma unroll
        for (int s = 0; s < OCAP; ++s) {
            const unsigned long long v = buf[s * NPAD + t];
            od[s] = (s < owptr) ? v : ~0ull;
        }
        owptr = 0;
#pragma unroll
        for (int k = 2; k <= 8; k <<= 1) {
#pragma unroll
            for (int j = k >> 1; j > 0; j >>= 1) {
#pragma unroll
                for (int i = 0; i < 8; ++i) {
                    const int l = i ^ j;
                    if (l > i) {
                        const bool up = ((i & k) == 0);
                        const unsigned long long a = od[i], c = od[l];
                        const bool sw = up ? (c < a) : (a < c);
                        od[i] = sw ? c : a;
                        od[l] = sw ? a : c;
                    }
                }
            }
        }
#pragma unroll
        for (int i = 8; i < 16; ++i) {
            const unsigned long long c = od[15 - i];
            bk[i] = (c < bk[i]) ? c : bk[i];
        }
#pragma unroll
        for (int j = 8; j > 0; j >>= 1) {
#pragma unroll
            for (int i = 0; i < 16; ++i) {
                const int l = i ^ j;
                if (l > i) {
                    const unsigned long long a = bk[i], c = bk[l];
                    const bool sw = (c < a);
                    bk[i] = sw ? c : a;
                    bk[l] = sw ? a : c;
                }
            }
        }
        unsigned int th = (unsigned int)(bk[15] >> 32);
#pragma unroll
        for (int m = 1; m <= 8; m <<= 1) {
            const unsigned int o = __shfl_xor(th, m, 16);
            th = (o < th) ? o : th;
        }
        thr_bits = th;
    };

    for (int rz = 0; rz < 3; ++rz) {
        for (int ry = 0; ry < 3; ++ry) {
            const int zz = cz + rz - 1, yy = cy + ry - 1;
            int rs = 0, re = 0;
            if (zz >= 0 && zz < GRD && yy >= 0 && yy < GRD) {
                const int rowb = ((zz << 3) + yy) << 3;
                rs = cs[rowb + x0];
                re = cs[rowb + x1 + 1];
            }
            int p = rs + l16;
            while (__any(p < re)) {
                if (p < re) {
                    const float4 c = sb[p];
                    const float dx = qx - c.x, dy = qy - c.y, dz = qz - c.z;
                    const float d2 = __fadd_rn(__fadd_rn(__fmul_rn(dx, dx), __fmul_rn(dy, dy)),
                                               __fmul_rn(dz, dz));
                    if (__float_as_uint(d2) < thr_bits) {
                        buf[owptr * NPAD + t] =
                            ((unsigned long long)__float_as_uint(d2) << 32) |
                            (unsigned int)__float_as_int(c.w);
                        owptr++;
                    }
                }
                p += 16;
                if (__any(owptr >= OCAP - 1)) compact();
            }
        }
    }
    compact();

    // 4-round cross-lane bitonic merge across the 16 lanes of the query.
#pragma unroll
    for (int m = 1; m <= 8; m <<= 1) {
        unsigned long long ot[16];
#pragma unroll
        for (int i = 0; i < 16; ++i) ot[i] = __shfl_xor(bk[i], m, 16);
#pragma unroll
        for (int i = 0; i < 16; ++i) {
            const unsigned long long c = ot[15 - i];
            bk[i] = (c < bk[i]) ? c : bk[i];
        }
#pragma unroll
        for (int j = 8; j > 0; j >>= 1) {
#pragma unroll
            for (int i = 0; i < 16; ++i) {
                const int l = i ^ j;
                if (l > i) {
                    const unsigned long long a = bk[i], c = bk[l];
                    const bool sw = (c < a);
                    bk[i] = sw ? c : a;
                    bk[l] = sw ? a : c;
                }
            }
        }
    }

    if (l16 == 0) {
        const int ob = q * NK;
        *(int4*)&idx_out[ob + 0]  = make_int4((int)bk[0],  (int)bk[1],  (int)bk[2],  (int)bk[3]);
        *(int4*)&idx_out[ob + 4]  = make_int4((int)bk[4],  (int)bk[5],  (int)bk[6],  (int)bk[7]);
        *(int4*)&idx_out[ob + 8]  = make_int4((int)bk[8],  (int)bk[9],  (int)bk[10], (int)bk[11]);
        *(int4*)&idx_out[ob + 12] = make_int4((int)bk[12], (int)bk[13], (int)bk[14], (int)bk[15]);

        const int y0 = max(0, cy - 1), y1 = min(GRD - 1, cy + 1);
        const int z0 = max(0, cz - 1), z1 = min(GRD - 1, cz + 1);
        float mg = 1e30f;
        if (x0 > 0)       mg = fminf(mg, qx - x0 * CELLH);
        if (x1 < GRD - 1) mg = fminf(mg, (x1 + 1) * CELLH - qx);
        if (y0 > 0)       mg = fminf(mg, qy - y0 * CELLH);
        if (y1 < GRD - 1) mg = fminf(mg, (y1 + 1) * CELLH - qy);
        if (z0 > 0)       mg = fminf(mg, qz - z0 * CELLH);
        if (z1 < GRD - 1) mg = fminf(mg, (z1 + 1) * CELLH - qz);
        mg = fmaxf(mg - 1e-5f, 0.f);
        const float mg2 = mg * mg;
        if ((unsigned int)(bk[15] >> 32) >= __float_as_uint(mg2)) {
            const int slot = atomicAdd(flagcnt, 1);
            flaglist[slot] = q;
        }
    }
}

// ---------------------------------------------------------------------------
// Kernel 1b: brute-force fallback, one block per flagged query (round 7).
// ---------------------------------------------------------------------------
__global__ __launch_bounds__(256) void knn_fallback(const float4* __restrict__ pos4,
                                                    int* __restrict__ idx_out,
                                                    const int* __restrict__ flagcnt,
                                                    const int* __restrict__ flaglist) {
    __shared__ unsigned long long wres[4 * 16];
    const int nf = flagcnt[0];
    const int t = threadIdx.x;
    const int w = t >> 6;

    for (int fi = blockIdx.x; fi < nf; fi += 64) {
        const int qi = flaglist[fi];
        const int b = qi >> 12;
        const float4* __restrict__ pb = pos4 + (b << 12);
        const float4 qp = pb[qi & 4095];

        float4 c[16];
#pragma unroll
        for (int s = 0; s < 16; ++s) c[s] = pb[(s << 8) | t];

        unsigned long long key[16];
#pragma unroll
        for (int s = 0; s < 16; ++s) {
            const int j = (s << 8) | t;
            const float dx = qp.x - c[s].x, dy = qp.y - c[s].y, dz = qp.z - c[s].z;
            const float d2 = __fadd_rn(__fadd_rn(__fmul_rn(dx, dx), __fmul_rn(dy, dy)),
                                       __fmul_rn(dz, dz));
            key[s] = ((unsigned long long)__float_as_uint(d2) << 32) | (unsigned int)j;
        }

#pragma unroll
        for (int k = 2; k <= 16; k <<= 1) {
#pragma unroll
            for (int j = k >> 1; j > 0; j >>= 1) {
#pragma unroll
                for (int i = 0; i < 16; ++i) {
                    const int l = i ^ j;
                    if (l > i) {
                        const bool up = ((i & k) == 0);
                        const unsigned long long a = key[i], cc = key[l];
                        const bool sw = up ? (cc < a) : (a < cc);
                        key[i] = sw ? cc : a;
                        key[l] = sw ? a : cc;
                    }
                }
            }
        }

#pragma unroll
        for (int m = 1; m <= 32; m <<= 1) {
            unsigned long long ot[16];
#pragma unroll
            for (int i = 0; i < 16; ++i) ot[i] = __shfl_xor(key[i], m, 64);
#pragma unroll
            for (int i = 0; i < 16; ++i) {
                const unsigned long long cc = ot[15 - i];
                key[i] = (cc < key[i]) ? cc : key[i];
            }
#pragma unroll
            for (int j = 8; j > 0; j >>= 1) {
#pragma unroll
                for (int i = 0; i < 16; ++i) {
                    const int l = i ^ j;
                    if (l > i) {
                        const unsigned long long a = key[i], cc = key[l];
                        const bool sw = (cc < a);
                        key[i] = sw ? cc : a;
                        key[l] = sw ? a : cc;
                    }
                }
            }
        }

        if ((t & 63) == 0) {
#pragma unroll
            for (int i = 0; i < 16; ++i) wres[w * 16 + i] = key[i];
        }
        __syncthreads();

        if (t == 0) {
            int hp[4] = {0, 0, 0, 0};
            const int ob = qi * NK;
            for (int o = 0; o < NK; ++o) {
                unsigned long long bestk = ~0ull;
                int bestw = 0;
#pragma unroll
                for (int w2 = 0; w2 < 4; ++w2) {
                    const unsigned long long h = (hp[w2] < 16) ? wres[w2 * 16 + hp[w2]] : ~0ull;
                    if (h < bestk) { bestk = h; bestw = w2; }
                }
                idx_out[ob + o] = (int)(bestk & 0xFFFFFFFFu);
                hp[bestw]++;
            }
        }
        __syncthreads();
    }
}

// ---------------------------------------------------------------------------
// Kernel 2: relation MLP via MFMA (16x16x32 bf16). (unchanged from round 9)
// ---------------------------------------------------------------------------
__device__ __forceinline__ unsigned int f2bf(float f) {   // RNE to bf16 bits
    unsigned int b = __float_as_uint(f);
    return (b + 0x7FFFu + ((b >> 16) & 1u)) >> 16;
}

__global__ __launch_bounds__(256) void mlp_kernel(
    const float4* __restrict__ pos4, const float* __restrict__ xpad,
    const int* __restrict__ idx,
    const float* __restrict__ rw1, const float* __restrict__ rb1,
    const float* __restrict__ rw2, const float* __restrict__ rb2,
    const float* __restrict__ rw3, const float* __restrict__ rb3,
    float* __restrict__ pooled) {
    __shared__ __attribute__((aligned(16))) unsigned short w2t[64 * 40];  // [n][k]
    __shared__ __attribute__((aligned(16))) unsigned short w3t[64 * 72];  // [n][k]
    __shared__ __attribute__((aligned(16))) unsigned short scr[4 * 64 * 72]; // per-wave

    const int t = threadIdx.x;
    for (int i = t; i < 64 * 32; i += 256) {
        const int n = i >> 5, k = i & 31;
        w2t[n * 40 + k] = (unsigned short)f2bf(rw2[k * 64 + n]);
    }
    for (int i = t; i < 64 * 64; i += 256) {
        const int n = i >> 6, k = i & 63;
        w3t[n * 72 + k] = (unsigned short)f2bf(rw3[k * 64 + n]);
    }
    __syncthreads();

    const int lane = t & 63;
    const int quad = lane >> 4;
    const int l16  = lane & 15;
    unsigned short* __restrict__ ws = &scr[(t >> 6) * 64 * 72];

    const int rowbase = blockIdx.x * 256 + (t & 192);   // (t>>6)*64
    const int b = rowbase >> 16;                        // 65536 items per batch
    const float4* __restrict__ pb = pos4 + ((size_t)b << 12);
    const float* __restrict__ xpb = xpad + (((size_t)b << 12) << 6);

    // layer-1 B fragment straight from global (once): k=quad*8+j
    bf16x8 b1f[2];
#pragma unroll
    for (int nt = 0; nt < 2; ++nt) {
        const int n = nt * 16 + l16;
#pragma unroll
        for (int j = 0; j < 8; ++j) {
            const int k = quad * 8 + j;
            float f = 0.f;
            if (k < 10) f = rw1[k * 32 + n];
            else if (k == 15) f = rb1[n];
            b1f[nt][j] = (short)f2bf(f);
        }
    }

    // ---- build rin rows (one per lane), bf16, stride 40; k15 = 1.0 ----
    {
        const int row_g = rowbase + lane;
        const int q = row_g >> 4;
        const int j = idx[row_g];
        const float4 cp = pb[q & 4095];
        const float4 gp = pb[j];
        const float rx = gp.x - cp.x, ry = gp.y - cp.y, rz = gp.z - cp.z;
        const float ss = rx * rx + ry * ry + rz * rz;
        const float dis = (ss > 0.f) ? sqrtf(ss) : 0.f;
        unsigned int d[20];
#pragma unroll
        for (int i = 0; i < 20; ++i) d[i] = 0;
        d[0] = f2bf(cp.x) | (f2bf(cp.y) << 16);
        d[1] = f2bf(cp.z) | (f2bf(gp.x) << 16);
        d[2] = f2bf(gp.y) | (f2bf(gp.z) << 16);
        d[3] = f2bf(rx)   | (f2bf(ry) << 16);
        d[4] = f2bf(rz)   | (f2bf(dis) << 16);
        d[7] = 0x3F800000u;   // k14=0, k15=1.0 (bias slot)
        unsigned int* wr = (unsigned int*)&ws[lane * 40];
#pragma unroll
        for (int i = 0; i < 20; ++i) wr[i] = d[i];
    }
    __builtin_amdgcn_s_waitcnt(0);   // lgkm drain before same-wave read-back

    const f32x4 zero = {0.f, 0.f, 0.f, 0.f};

    // ---- layer 1: 64x32 = A(64x32) @ w1(32x32-padded) ----
    bf16x8 a1[4];
#pragma unroll
    for (int mt = 0; mt < 4; ++mt)
        a1[mt] = *(const bf16x8*)&ws[(mt * 16 + l16) * 40 + quad * 8];

    f32x4 c1[2][4];
#pragma unroll
    for (int nt = 0; nt < 2; ++nt)
#pragma unroll
        for (int mt = 0; mt < 4; ++mt)
            c1[nt][mt] = __builtin_amdgcn_mfma_f32_16x16x32_bf16(a1[mt], b1f[nt], zero, 0, 0, 0);

    // relu -> h1 to LDS (stride 40)
#pragma unroll
    for (int nt = 0; nt < 2; ++nt)
#pragma unroll
        for (int mt = 0; mt < 4; ++mt)
#pragma unroll
            for (int r = 0; r < 4; ++r)
                ws[(mt * 16 + quad * 4 + r) * 40 + nt * 16 + l16] =
                    (unsigned short)f2bf(fmaxf(c1[nt][mt][r], 0.f));
    __builtin_amdgcn_s_waitcnt(0);

    // ---- layer 2: 64x64 = h1(64x32) @ w2(32x64) ----
    float b2v[4], b3v[4];
#pragma unroll
    for (int nt = 0; nt < 4; ++nt) { b2v[nt] = rb2[nt * 16 + l16]; b3v[nt] = rb3[nt * 16 + l16]; }

    bf16x8 a2[4];
#pragma unroll
    for (int mt = 0; mt < 4; ++mt)
        a2[mt] = *(const bf16x8*)&ws[(mt * 16 + l16) * 40 + quad * 8];

    f32x4 c2[4][4];
#pragma unroll
    for (int nt = 0; nt < 4; ++nt) {
        const bf16x8 b2f = *(const bf16x8*)&w2t[(nt * 16 + l16) * 40 + quad * 8];
#pragma unroll
        for (int mt = 0; mt < 4; ++mt)
            c2[nt][mt] = __builtin_amdgcn_mfma_f32_16x16x32_bf16(a2[mt], b2f, zero, 0, 0, 0);
    }

    // bias + relu -> h2 to LDS (stride 72)
#pragma unroll
    for (int nt = 0; nt < 4; ++nt)
#pragma unroll
        for (int mt = 0; mt < 4; ++mt)
#pragma unroll
            for (int r = 0; r < 4; ++r)
                ws[(mt * 16 + quad * 4 + r) * 72 + nt * 16 + l16] =
                    (unsigned short)f2bf(fmaxf(c2[nt][mt][r] + b2v[nt], 0.f));
    __builtin_amdgcn_s_waitcnt(0);

    // ---- layer 3: 64x64 = h2(64x64) @ w3(64x64), 2 k-tiles ----
    bf16x8 a3[4][2];
#pragma unroll
    for (int mt = 0; mt < 4; ++mt)
#pragma unroll
        for (int kt = 0; kt < 2; ++kt)
            a3[mt][kt] = *(const bf16x8*)&ws[(mt * 16 + l16) * 72 + kt * 32 + quad * 8];

    f32x4 c3[4][4];
#pragma unroll
    for (int nt = 0; nt < 4; ++nt) {
        const bf16x8 b3f0 = *(const bf16x8*)&w3t[(nt * 16 + l16) * 72 + 0 * 32 + quad * 8];
        const bf16x8 b3f1 = *(const bf16x8*)&w3t[(nt * 16 + l16) * 72 + 1 * 32 + quad * 8];
#pragma unroll
        for (int mt = 0; mt < 4; ++mt) {
            f32x4 acc = __builtin_amdgcn_mfma_f32_16x16x32_bf16(a3[mt][0], b3f0, zero, 0, 0, 0);
            c3[nt][mt] = __builtin_amdgcn_mfma_f32_16x16x32_bf16(a3[mt][1], b3f1, acc, 0, 0, 0);
        }
    }

    // ---- feat multiply + max-pool over the 16 rows of each m-tile ----
#pragma unroll
    for (int mt = 0; mt < 4; ++mt) {
        const int qg = (rowbase >> 4) + mt;     // m-tile == one query
        int jrow[4];
#pragma unroll
        for (int r = 0; r < 4; ++r) jrow[r] = idx[rowbase + mt * 16 + quad * 4 + r];
#pragma unroll
        for (int nt = 0; nt < 4; ++nt) {
            const int col = nt * 16 + l16;
            float mx = -1e30f;
#pragma unroll
            for (int r = 0; r < 4; ++r) {
                const float fv = xpb[((size_t)jrow[r] << 6) + col];
                mx = fmaxf(mx, fv * (c3[nt][mt][r] + b3v[nt]));
            }
            mx = fmaxf(mx, __shfl_xor(mx, 16, 64));
            mx = fmaxf(mx, __shfl_xor(mx, 32, 64));
            mx = fmaxf(mx, 0.f);                // relu AFTER pool
            if (quad == 0) pooled[(size_t)qg * 64 + col] = mx;
        }
    }
}

// ---------------------------------------------------------------------------
// Kernel 3: y1 = pooled(16384x64) @ fw1(64x128) + fb1 ; accumulate sum/sumsq.
// ---------------------------------------------------------------------------
__global__ __launch_bounds__(256) void gemm1_kernel(
    const float* __restrict__ A, const float* __restrict__ W,
    const float* __restrict__ bias, float* __restrict__ y,
    float* __restrict__ sum, float* __restrict__ sumsq) {
    __shared__ float As[32 * 64];
    __shared__ float Bs[64 * 128];
    const int t = threadIdx.x;
    const int r0 = blockIdx.x * 32;
    for (int i = t; i < 64 * 128; i += 256) Bs[i] = W[i];
    for (int i = t; i < 32 * 64; i += 256)  As[i] = A[(size_t)r0 * 64 + i];
    __syncthreads();

    const int c = t & 127, rg = t >> 7;
    float acc[16];
    const float bv = bias[c];
#pragma unroll
    for (int r = 0; r < 16; ++r) acc[r] = bv;

    for (int kk = 0; kk < 64; kk += 4) {
        const float b0 = Bs[(kk + 0) * 128 + c];
        const float b1 = Bs[(kk + 1) * 128 + c];
        const float b2 = Bs[(kk + 2) * 128 + c];
        const float b3 = Bs[(kk + 3) * 128 + c];
#pragma unroll
        for (int r = 0; r < 16; ++r) {
            const float4 a = *(const float4*)&As[(rg * 16 + r) * 64 + kk];
            acc[r] += a.x * b0 + a.y * b1 + a.z * b2 + a.w * b3;
        }
    }

    float s = 0.f, s2 = 0.f;
#pragma unroll
    for (int r = 0; r < 16; ++r) {
        const float v = acc[r];
        s += v; s2 += v * v;
        y[(size_t)(r0 + rg * 16 + r) * 128 + c] = v;
    }
    __syncthreads();
    As[t] = s; As[256 + t] = s2;
    __syncthreads();
    if (rg == 0) {
        atomicAdd(&sum[c],   As[c] + As[128 + c]);
        atomicAdd(&sumsq[c], As[256 + c] + As[256 + 128 + c]);
    }
}

// ---------------------------------------------------------------------------
// Kernel 4: h1 = relu(bn1(y1)); y2 = h1 @ fw2(128x128) + fb2 ; sum/sumsq.
// ---------------------------------------------------------------------------
__global__ __launch_bounds__(256) void gemm2_kernel(
    const float* __restrict__ y1, const float* __restrict__ W,
    const float* __restrict__ bias,
    const float* __restrict__ sum1, const float* __restrict__ sumsq1,
    const float* __restrict__ g1, const float* __restrict__ b1,
    float* __restrict__ y2, float* __restrict__ sum2, float* __restrict__ sumsq2) {
    __shared__ float As[32 * 128];
    __shared__ float Bs[64 * 128];
    __shared__ float a1s[128], s1s[128];
    const int t = threadIdx.x;
    const int r0 = blockIdx.x * 32;

    if (t < 128) {
        const float m = sum1[t] * INV_ROWS;
        const float v = sumsq1[t] * INV_ROWS - m * m;
        const float a = rsqrtf(v + BN_EPS) * g1[t];
        a1s[t] = a; s1s[t] = b1[t] - m * a;
    }
    for (int i = t; i < 64 * 128; i += 256) Bs[i] = W[i];
    __syncthreads();
    for (int i = t; i < 32 * 128; i += 256) {
        const int cc = i & 127;
        const float v = y1[(size_t)r0 * 128 + i];
        As[i] = fmaxf(v * a1s[cc] + s1s[cc], 0.f);
    }
    __syncthreads();

    const int c = t & 127, rg = t >> 7;
    float acc[16];
    const float bv = bias[c];
#pragma unroll
    for (int r = 0; r < 16; ++r) acc[r] = bv;

    for (int kk = 0; kk < 64; kk += 4) {
        const float b0 = Bs[(kk + 0) * 128 + c];
        const float b1v = Bs[(kk + 1) * 128 + c];
        const float b2 = Bs[(kk + 2) * 128 + c];
        const float b3 = Bs[(kk + 3) * 128 + c];
#pragma unroll
        for (int r = 0; r < 16; ++r) {
            const float4 a = *(const float4*)&As[(rg * 16 + r) * 128 + kk];
            acc[r] += a.x * b0 + a.y * b1v + a.z * b2 + a.w * b3;
        }
    }
    __syncthreads();
    for (int i = t; i < 64 * 128; i += 256) Bs[i] = W[64 * 128 + i];
    __syncthreads();
    for (int kk = 0; kk < 64; kk += 4) {
        const float b0 = Bs[(kk + 0) * 128 + c];
        const float b1v = Bs[(kk + 1) * 128 + c];
        const float b2 = Bs[(kk + 2) * 128 + c];
        const float b3 = Bs[(kk + 3) * 128 + c];
#pragma unroll
        for (int r = 0; r < 16; ++r) {
            const float4 a = *(const float4*)&As[(rg * 16 + r) * 128 + 64 + kk];
            acc[r] += a.x * b0 + a.y * b1v + a.z * b2 + a.w * b3;
        }
    }

    float s = 0.f, s2 = 0.f;
#pragma unroll
    for (int r = 0; r < 16; ++r) {
        const float v = acc[r];
        s += v; s2 += v * v;
        y2[(size_t)(r0 + rg * 16 + r) * 128 + c] = v;
    }
    __syncthreads();
    As[t] = s; As[256 + t] = s2;
    __syncthreads();
    if (rg == 0) {
        atomicAdd(&sum2[c],   As[c] + As[128 + c]);
        atomicAdd(&sumsq2[c], As[256 + c] + As[256 + 128 + c]);
    }
}

// ---------------------------------------------------------------------------
// Kernel 5: out = bn2(y2)
// ---------------------------------------------------------------------------
__global__ __launch_bounds__(256) void bnout_kernel(
    const float* __restrict__ y2, const float* __restrict__ sum2,
    const float* __restrict__ sumsq2, const float* __restrict__ g2,
    const float* __restrict__ b2, float* __restrict__ out) {
    const int i = blockIdx.x * 256 + threadIdx.x;
    const int c = i & 127;
    const float m = sum2[c] * INV_ROWS;
    const float v = sumsq2[c] * INV_ROWS - m * m;
    const float a = rsqrtf(v + BN_EPS) * g2[c];
    out[i] = y2[i] * a + (b2[c] - m * a);
}

extern "C" void kernel_launch(void* const* d_in, const int* in_sizes, int n_in,
                              void* d_out, int out_size, void* d_ws, size_t ws_size,
                              hipStream_t stream) {
    const float* x   = (const float*)d_in[0];
    const float* pos = (const float*)d_in[1];
    const float* rw1 = (const float*)d_in[2];
    const float* rb1 = (const float*)d_in[3];
    const float* rw2 = (const float*)d_in[4];
    const float* rb2 = (const float*)d_in[5];
    const float* rw3 = (const float*)d_in[6];
    const float* rb3 = (const float*)d_in[7];
    const float* fw1 = (const float*)d_in[8];
    const float* fb1 = (const float*)d_in[9];
    const float* g1  = (const float*)d_in[10];
    const float* b1  = (const float*)d_in[11];
    const float* fw2 = (const float*)d_in[12];
    const float* fb2 = (const float*)d_in[13];
    const float* g2  = (const float*)d_in[14];
    const float* b2  = (const float*)d_in[15];
    float* out = (float*)d_out;

    char* ws = (char*)d_ws;
    int*    idx      = (int*)ws;                           // 1 MB
    float*  pooled   = (float*)(ws + (1u << 20));          // 4 MB
    float*  y1       = (float*)(ws + (5u << 20));          // 8 MB
    float*  y2       = (float*)(ws + (13u << 20));         // 8 MB
    float*  stats    = (float*)(ws + (21u << 20));         // zeroed block start
    float*  sum1 = stats, *sumsq1 = stats + 128, *sum2 = stats + 256, *sumsq2 = stats + 384;
    int*    counts   = (int*)(stats + 512);                // 4*512
    int*    fill     = counts + NB * NCELL;                // 4*512
    int*    flagcnt  = fill + NB * NCELL;                  // 1
    int*    cellStart= (int*)(ws + (21u << 20) + (20u << 10));  // 4*513 ints
    int*    cellOf   = (int*)(ws + (21u << 20) + (32u << 10));  // 16384 ints
    int*    flaglist = (int*)(ws + (21u << 20) + (96u << 10));  // 16384 ints
    float4* pos4     = (float4*)(ws + (22u << 20));        // 256 KB
    float4* spt      = (float4*)(ws + (22u << 20) + (256u << 10)); // 256 KB
    float*  xpad     = (float*)(ws + (23u << 20));         // 16384*64 f32 (4 MB)

    hipMemsetAsync(stats, 0, (512 + 2048 + 2048 + 1) * sizeof(float), stream);

    prep_kernel<<<4096, 256, 0, stream>>>(pos, x, pos4, cellOf, counts, xpad);
    scan_kernel<<<NB, 512, 0, stream>>>(counts, cellStart);
    scatter_kernel<<<64, 256, 0, stream>>>(pos4, cellOf, cellStart, fill, spt);
    knn_kernel<<<1024, 256, 0, stream>>>(pos4, spt, cellStart, idx, flagcnt, flaglist);
    knn_fallback<<<64, 256, 0, stream>>>(pos4, idx, flagcnt, flaglist);
    mlp_kernel<<<1024, 256, 0, stream>>>(pos4, xpad, idx, rw1, rb1, rw2, rb2, rw3, rb3, pooled);
    gemm1_kernel<<<512, 256, 0, stream>>>(pooled, fw1, fb1, y1, sum1, sumsq1);
    gemm2_kernel<<<512, 256, 0, stream>>>(y1, fw2, fb2, sum1, sumsq1, g1, b1, y2, sum2, sumsq2);
    bnout_kernel<<<NROWS * 128 / 256, 256, 0, stream>>>(y2, sum2, sumsq2, g2, b2, out);
}